// Round 1
// baseline (766.145 us; speedup 1.0000x reference)
//
#include <hip/hip_runtime.h>
#include <math.h>

// Problem constants (LegalGAT): N=50000 nodes, E=800000 edges, F_IN=256, HID=64, HEADS=4.

__device__ __forceinline__ float leaky02(float t) { return t > 0.f ? t : 0.2f * t; }
__device__ __forceinline__ float elu1(float t) { return t > 0.f ? t : (__expf(t) - 1.f); }

// ---------------- CSR build ----------------

__global__ __launch_bounds__(256) void count_kernel(const int* __restrict__ dst,
                                                    int* __restrict__ count, int E) {
  int e = blockIdx.x * blockDim.x + threadIdx.x;
  if (e < E) atomicAdd(&count[dst[e]], 1);
}

// Single-block exclusive scan over (count[i]+1) (the +1 is the self-loop),
// writes offsets[0..n] and the self-loop entry csr[offsets[i]] = i.
__global__ __launch_bounds__(1024) void scan_selfloop_kernel(const int* __restrict__ count,
                                                             int* __restrict__ offsets,
                                                             int* __restrict__ csr_src, int n) {
  const int T = 1024;
  __shared__ int part[T];
  int tid = threadIdx.x;
  int chunk = (n + T - 1) / T;
  int b = tid * chunk;
  int e = min(b + chunk, n);
  int sum = 0;
  for (int i = b; i < e; ++i) sum += 1 + count[i];
  part[tid] = sum;
  __syncthreads();
  for (int off = 1; off < T; off <<= 1) {
    int v = (tid >= off) ? part[tid - off] : 0;
    __syncthreads();
    part[tid] += v;
    __syncthreads();
  }
  int run = (tid == 0) ? 0 : part[tid - 1];
  for (int i = b; i < e; ++i) {
    offsets[i] = run;
    csr_src[run] = i;  // self loop occupies slot 0 of segment i
    run += 1 + count[i];
  }
  if (tid == T - 1) offsets[n] = run;
}

__global__ __launch_bounds__(256) void scatter_kernel(const int* __restrict__ src,
                                                      const int* __restrict__ dst,
                                                      const int* __restrict__ offsets,
                                                      int* __restrict__ cursor,
                                                      int* __restrict__ csr_src, int E) {
  int e = blockIdx.x * blockDim.x + threadIdx.x;
  if (e < E) {
    int d = dst[e];
    int pos = atomicAdd(&cursor[d], 1);
    csr_src[offsets[d] + 1 + pos] = src[e];
  }
}

// ---------------- fp32 tiled GEMM: C[M,N] = A[M,K] * B[K,N] ----------------
// BM=64, BN=64, BK=16, 256 threads, each thread 4x4 outputs.
__global__ __launch_bounds__(256) void gemm_f32(const float* __restrict__ A,
                                                const float* __restrict__ B,
                                                float* __restrict__ C, int M, int N, int K) {
  constexpr int BM = 64, BN = 64, BK = 16;
  __shared__ float As[BK][BM];
  __shared__ float Bs[BK][BN];
  int tid = threadIdx.x;
  int bm = blockIdx.x * BM;
  int bn = blockIdx.y * BN;
  int tm = (tid >> 4) * 4;
  int tn = (tid & 15) * 4;
  int am = tid >> 2;          // row within A tile
  int ak = (tid & 3) * 4;     // k within A tile
  int bk = tid >> 4;          // k within B tile
  int bnn = (tid & 15) * 4;   // col within B tile
  float acc[4][4] = {};
  for (int k0 = 0; k0 < K; k0 += BK) {
    float4 av;
    if (bm + am < M) av = *(const float4*)&A[(size_t)(bm + am) * K + k0 + ak];
    else av = make_float4(0.f, 0.f, 0.f, 0.f);
    float4 bv = *(const float4*)&B[(size_t)(k0 + bk) * N + bn + bnn];
    As[ak + 0][am] = av.x;
    As[ak + 1][am] = av.y;
    As[ak + 2][am] = av.z;
    As[ak + 3][am] = av.w;
    *(float4*)&Bs[bk][bnn] = bv;
    __syncthreads();
#pragma unroll
    for (int k = 0; k < BK; ++k) {
      float ar[4] = {As[k][tm], As[k][tm + 1], As[k][tm + 2], As[k][tm + 3]};
      float br[4] = {Bs[k][tn], Bs[k][tn + 1], Bs[k][tn + 2], Bs[k][tn + 3]};
#pragma unroll
      for (int i = 0; i < 4; ++i)
#pragma unroll
        for (int j = 0; j < 4; ++j)
          acc[i][j] = fmaf(ar[i], br[j], acc[i][j]);
    }
    __syncthreads();
  }
#pragma unroll
  for (int i = 0; i < 4; ++i) {
    int m = bm + tm + i;
    if (m < M)
      *(float4*)&C[(size_t)m * N + bn + tn] =
          make_float4(acc[i][0], acc[i][1], acc[i][2], acc[i][3]);
  }
}

// ---------------- attention alpha dot products ----------------
// wave per node; H heads of 64 channels.
template <int H>
__global__ __launch_bounds__(256) void alpha_kernel(const float* __restrict__ xh,
                                                    const float* __restrict__ a_src,
                                                    const float* __restrict__ a_dst,
                                                    float* __restrict__ al_s,
                                                    float* __restrict__ al_d, int n) {
  int w = (blockIdx.x * blockDim.x + threadIdx.x) >> 6;
  int lane = threadIdx.x & 63;
  if (w >= n) return;
  float s[H], d[H];
#pragma unroll
  for (int h = 0; h < H; ++h) {
    float v = xh[(size_t)w * (H * 64) + h * 64 + lane];
    s[h] = v * a_src[h * 64 + lane];
    d[h] = v * a_dst[h * 64 + lane];
  }
#pragma unroll
  for (int off = 32; off; off >>= 1) {
#pragma unroll
    for (int h = 0; h < H; ++h) {
      s[h] += __shfl_xor(s[h], off);
      d[h] += __shfl_xor(d[h], off);
    }
  }
  if (lane == 0) {
#pragma unroll
    for (int h = 0; h < H; ++h) {
      al_s[w * H + h] = s[h];
      al_d[w * H + h] = d[h];
    }
  }
}

// ---------------- segment-softmax aggregation ----------------
// wave per dst node, two passes over its CSR segment: (1) max, (2) exp-sum + weighted acc.
template <int H>
__global__ __launch_bounds__(256) void agg_kernel(const float* __restrict__ xh,
                                                  const float* __restrict__ al_s,
                                                  const float* __restrict__ al_d,
                                                  const int* __restrict__ offsets,
                                                  const int* __restrict__ csr_src,
                                                  const float* __restrict__ bias,
                                                  float* __restrict__ out, int n) {
  int node = (blockIdx.x * blockDim.x + threadIdx.x) >> 6;
  int lane = threadIdx.x & 63;
  if (node >= n) return;
  int beg = offsets[node], end = offsets[node + 1];
  float ad[H], m[H], den[H], acc[H];
#pragma unroll
  for (int h = 0; h < H; ++h) {
    ad[h] = al_d[node * H + h];
    m[h] = -1e30f;
    den[h] = 0.f;
    acc[h] = 0.f;
  }
  for (int e = beg; e < end; ++e) {
    int s = csr_src[e];
#pragma unroll
    for (int h = 0; h < H; ++h) {
      float t = leaky02(al_s[s * H + h] + ad[h]);
      m[h] = fmaxf(m[h], t);
    }
  }
  for (int e = beg; e < end; ++e) {
    int s = csr_src[e];
#pragma unroll
    for (int h = 0; h < H; ++h) {
      float t = leaky02(al_s[s * H + h] + ad[h]);
      float ex = __expf(t - m[h]);
      den[h] += ex;
      acc[h] += ex * xh[(size_t)s * (H * 64) + h * 64 + lane];
    }
  }
#pragma unroll
  for (int h = 0; h < H; ++h) {
    float o = acc[h] / (den[h] + 1e-16f) + bias[h * 64 + lane];
    out[(size_t)node * (H * 64) + h * 64 + lane] = elu1(o);
  }
}

// ---------------- launch ----------------

extern "C" void kernel_launch(void* const* d_in, const int* in_sizes, int n_in,
                              void* d_out, int out_size, void* d_ws, size_t ws_size,
                              hipStream_t stream) {
  const float* x   = (const float*)d_in[0];
  const int*   ei  = (const int*)d_in[1];
  const float* W1  = (const float*)d_in[2];
  const float* as1 = (const float*)d_in[3];
  const float* ad1 = (const float*)d_in[4];
  const float* b1  = (const float*)d_in[5];
  const float* W2  = (const float*)d_in[6];
  const float* as2 = (const float*)d_in[7];
  const float* ad2 = (const float*)d_in[8];
  const float* b2  = (const float*)d_in[9];
  float* out = (float*)d_out;

  const int E = in_sizes[1] / 2;    // 800000
  const int n = in_sizes[0] / 256;  // 50000

  size_t off = 0;
  auto alloc = [&](size_t bytes) -> void* {
    void* p = (char*)d_ws + off;
    off += (bytes + 511) & ~(size_t)511;
    return p;
  };
  float* xh    = (float*)alloc((size_t)n * 256 * 4);  // xh1; reused as xh2 after agg1
  float* hbuf  = (float*)alloc((size_t)n * 256 * 4);  // layer-1 output
  float* als1v = (float*)alloc((size_t)n * 4 * 4);
  float* ald1v = (float*)alloc((size_t)n * 4 * 4);
  float* als2v = (float*)alloc((size_t)n * 4);
  float* ald2v = (float*)alloc((size_t)n * 4);
  int* count   = (int*)alloc((size_t)n * 4);
  int* cursor  = (int*)alloc((size_t)n * 4);
  int* offsets = (int*)alloc((size_t)(n + 1) * 4);
  int* csr     = (int*)alloc((size_t)(E + n) * 4);

  const int* srcv = ei;
  const int* dstv = ei + E;

  hipMemsetAsync(count, 0, (size_t)n * 4, stream);
  hipMemsetAsync(cursor, 0, (size_t)n * 4, stream);

  count_kernel<<<(E + 255) / 256, 256, 0, stream>>>(dstv, count, E);
  scan_selfloop_kernel<<<1, 1024, 0, stream>>>(count, offsets, csr, n);
  scatter_kernel<<<(E + 255) / 256, 256, 0, stream>>>(srcv, dstv, offsets, cursor, csr, E);

  // Layer 1
  gemm_f32<<<dim3((n + 63) / 64, 4), 256, 0, stream>>>(x, W1, xh, n, 256, 256);
  alpha_kernel<4><<<(n + 3) / 4, 256, 0, stream>>>(xh, as1, ad1, als1v, ald1v, n);
  agg_kernel<4><<<(n + 3) / 4, 256, 0, stream>>>(xh, als1v, ald1v, offsets, csr, b1, hbuf, n);

  // Layer 2
  gemm_f32<<<dim3((n + 63) / 64, 1), 256, 0, stream>>>(hbuf, W2, xh, n, 64, 256);
  alpha_kernel<1><<<(n + 3) / 4, 256, 0, stream>>>(xh, as2, ad2, als2v, ald2v, n);
  agg_kernel<1><<<(n + 3) / 4, 256, 0, stream>>>(xh, als2v, ald2v, offsets, csr, b2, out, n);
}

// Round 4
// 459.542 us; speedup vs baseline: 1.6672x; 1.6672x over previous
//
#include <hip/hip_runtime.h>
#include <math.h>

// LegalGAT: N=50000, E=800000, F_IN=256, HID=64, HEADS=4.
// Pipeline: CSR build -> split-bf16 MFMA GEMM1 -> alpha1 -> agg1 (fused h->bf16 hi/lo)
//           -> MFMA GEMM2 -> alpha2 -> agg2.

using short8_t = __attribute__((ext_vector_type(8))) short;
using f32x4   = __attribute__((ext_vector_type(4))) float;
using ushort4v = __attribute__((ext_vector_type(4))) unsigned short;

__device__ __forceinline__ float leaky02(float t) { return t > 0.f ? t : 0.2f * t; }
__device__ __forceinline__ float elu1(float t) { return t > 0.f ? t : (__expf(t) - 1.f); }

__device__ __forceinline__ unsigned short bf16_rne(float f) {
  unsigned u = __float_as_uint(f);
  unsigned r = u + 0x7FFFu + ((u >> 16) & 1u);
  return (unsigned short)(r >> 16);
}
__device__ __forceinline__ float bf16_to_f(unsigned short h) {
  return __uint_as_float(((unsigned)h) << 16);
}

// ---------------- CSR build ----------------

__global__ __launch_bounds__(256) void count_kernel(const int* __restrict__ dst,
                                                    int* __restrict__ count, int E) {
  int e = blockIdx.x * blockDim.x + threadIdx.x;
  if (e < E) atomicAdd(&count[dst[e]], 1);
}

// per-block inclusive scan of (1+count) -> local exclusive prefix + block sums
__global__ __launch_bounds__(256) void scan1_kernel(const int* __restrict__ count,
                                                    int* __restrict__ locpre,
                                                    int* __restrict__ bsum, int n) {
  __shared__ int sh[256];
  int t = threadIdx.x;
  int node = blockIdx.x * 256 + t;
  int v = (node < n) ? (1 + count[node]) : 0;
  sh[t] = v;
  __syncthreads();
  for (int off = 1; off < 256; off <<= 1) {
    int u = (t >= off) ? sh[t - off] : 0;
    __syncthreads();
    sh[t] += u;
    __syncthreads();
  }
  if (node < n) locpre[node] = sh[t] - v;
  if (t == 255) bsum[blockIdx.x] = sh[255];
}

__global__ __launch_bounds__(256) void scan2_kernel(int* __restrict__ bsum, int nb) {
  __shared__ int sh[256];
  int t = threadIdx.x;
  int v = (t < nb) ? bsum[t] : 0;
  sh[t] = v;
  __syncthreads();
  for (int off = 1; off < 256; off <<= 1) {
    int u = (t >= off) ? sh[t - off] : 0;
    __syncthreads();
    sh[t] += u;
    __syncthreads();
  }
  if (t < nb) bsum[t] = sh[t] - v;  // exclusive
}

__global__ __launch_bounds__(256) void scan3_kernel(const int* __restrict__ locpre,
                                                    const int* __restrict__ bsum,
                                                    int* __restrict__ offsets,
                                                    int* __restrict__ csr,
                                                    int* __restrict__ cursor,
                                                    int n, int Etot) {
  int node = blockIdx.x * 256 + threadIdx.x;
  if (node >= n) return;
  int o = bsum[blockIdx.x] + locpre[node];
  offsets[node] = o;
  csr[o] = node;  // self-loop in slot 0
  cursor[node] = 0;
  if (node == n - 1) offsets[n] = Etot;
}

__global__ __launch_bounds__(256) void scatter_kernel(const int* __restrict__ src,
                                                      const int* __restrict__ dst,
                                                      const int* __restrict__ offsets,
                                                      int* __restrict__ cursor,
                                                      int* __restrict__ csr, int E) {
  int e = blockIdx.x * blockDim.x + threadIdx.x;
  if (e < E) {
    int d = dst[e];
    int pos = atomicAdd(&cursor[d], 1);
    csr[offsets[d] + 1 + pos] = src[e];
  }
}

// ---------------- conversions to split-bf16 ----------------
// Acat row layout along K': [Ah(256) | Al(256) | Ah(256)]
__global__ __launch_bounds__(256) void convA_kernel(const float* __restrict__ X,
                                                    unsigned short* __restrict__ Acat, int M) {
  int idx = blockIdx.x * blockDim.x + threadIdx.x;
  if (idx >= M * 64) return;
  int m = idx >> 6;
  int c4 = (idx & 63) * 4;
  float4 v = *(const float4*)&X[(size_t)m * 256 + c4];
  ushort4v hi, lo;
  hi[0] = bf16_rne(v.x); lo[0] = bf16_rne(v.x - bf16_to_f(hi[0]));
  hi[1] = bf16_rne(v.y); lo[1] = bf16_rne(v.y - bf16_to_f(hi[1]));
  hi[2] = bf16_rne(v.z); lo[2] = bf16_rne(v.z - bf16_to_f(hi[2]));
  hi[3] = bf16_rne(v.w); lo[3] = bf16_rne(v.w - bf16_to_f(hi[3]));
  size_t base = (size_t)m * 768 + c4;
  *(ushort4v*)&Acat[base]       = hi;
  *(ushort4v*)&Acat[base + 256] = lo;
  *(ushort4v*)&Acat[base + 512] = hi;
}

// W [K=256][N] -> Bt [N][768] with k-layout [Bh | Bh | Bl]
__global__ __launch_bounds__(256) void convB_kernel(const float* __restrict__ W,
                                                    unsigned short* __restrict__ Bt, int N) {
  int idx = blockIdx.x * blockDim.x + threadIdx.x;
  if (idx >= N * 64) return;
  int n = idx >> 6;
  int k4 = (idx & 63) * 4;
  ushort4v hi, lo;
#pragma unroll
  for (int i = 0; i < 4; ++i) {
    float w = W[(size_t)(k4 + i) * N + n];
    hi[i] = bf16_rne(w);
    lo[i] = bf16_rne(w - bf16_to_f(hi[i]));
  }
  size_t base = (size_t)n * 768 + k4;
  *(ushort4v*)&Bt[base]       = hi;
  *(ushort4v*)&Bt[base + 256] = hi;
  *(ushort4v*)&Bt[base + 512] = lo;
}

// ---------------- bf16 MFMA GEMM: C[M,N] = Acat[M,768] * Bt[N,768]^T ----------------
// BM=128, BK=32, 256 threads = 4 waves (WR x WC). XOR chunk swizzle on 16B units.
template <int BN, int WR, int WC>
__global__ __launch_bounds__(256) void gemm_bf16(const unsigned short* __restrict__ A,
                                                 const unsigned short* __restrict__ Bt,
                                                 float* __restrict__ C, int M, int N) {
  constexpr int BM = 128, BK = 32, KTOT = 768;
  constexpr int WM = BM / WR, WN = BN / WC;
  constexpr int MR = WM / 16, NR = WN / 16;
  constexpr int ACH = (BM * 4) / 256;  // A 16B-chunks per thread
  constexpr int BCH = (BN * 4) / 256;  // B 16B-chunks per thread
  __shared__ __align__(16) unsigned short lsA[BM * BK];
  __shared__ __align__(16) unsigned short lsB[BN * BK];
  const int tid = threadIdx.x;
  const int lane = tid & 63;
  const int w = tid >> 6;
  const int wr = w / WC, wc = w % WC;
  const int bm = blockIdx.x * BM;
  const int bn = blockIdx.y * BN;

  f32x4 acc[MR][NR];
#pragma unroll
  for (int i = 0; i < MR; ++i)
#pragma unroll
    for (int j = 0; j < NR; ++j) acc[i][j] = (f32x4){0.f, 0.f, 0.f, 0.f};

  for (int k0 = 0; k0 < KTOT; k0 += BK) {
#pragma unroll
    for (int i = 0; i < ACH; ++i) {
      int id = tid + i * 256;
      int row = id >> 2, c0 = id & 3;
      int cs = c0 ^ ((row >> 1) & 3);
      *(int4*)&lsA[row * BK + cs * 8] =
          *(const int4*)&A[(size_t)(bm + row) * KTOT + k0 + c0 * 8];
    }
#pragma unroll
    for (int i = 0; i < BCH; ++i) {
      int id = tid + i * 256;
      int row = id >> 2, c0 = id & 3;
      int cs = c0 ^ ((row >> 1) & 3);
      *(int4*)&lsB[row * BK + cs * 8] =
          *(const int4*)&Bt[(size_t)(bn + row) * KTOT + k0 + c0 * 8];
    }
    __syncthreads();
    short8_t af[MR], bf[NR];
#pragma unroll
    for (int mr = 0; mr < MR; ++mr) {
      int rr = wr * WM + mr * 16 + (lane & 15);
      int kc = (lane >> 4) ^ ((rr >> 1) & 3);
      af[mr] = *(const short8_t*)&lsA[rr * BK + kc * 8];
    }
#pragma unroll
    for (int nr = 0; nr < NR; ++nr) {
      int rn = wc * WN + nr * 16 + (lane & 15);
      int kc = (lane >> 4) ^ ((rn >> 1) & 3);
      bf[nr] = *(const short8_t*)&lsB[rn * BK + kc * 8];
    }
#pragma unroll
    for (int mr = 0; mr < MR; ++mr)
#pragma unroll
      for (int nr = 0; nr < NR; ++nr)
        acc[mr][nr] = __builtin_amdgcn_mfma_f32_16x16x32_bf16(af[mr], bf[nr], acc[mr][nr], 0, 0, 0);
    __syncthreads();
  }
#pragma unroll
  for (int mr = 0; mr < MR; ++mr) {
#pragma unroll
    for (int j = 0; j < 4; ++j) {
      int r = bm + wr * WM + mr * 16 + (lane >> 4) * 4 + j;
      if (r < M) {
#pragma unroll
        for (int nr = 0; nr < NR; ++nr) {
          int c = bn + wc * WN + nr * 16 + (lane & 15);
          C[(size_t)r * N + c] = acc[mr][nr][j];
        }
      }
    }
  }
}

// ---------------- alpha dot products ----------------
// H=4: wave per node, lane owns 4 contiguous channels; reduce within 16-lane head group.
__global__ __launch_bounds__(256) void alpha1_kernel(const float* __restrict__ xh,
                                                     const float* __restrict__ asrc,
                                                     const float* __restrict__ adst,
                                                     float* __restrict__ als,
                                                     float* __restrict__ ald, int n) {
  int wv = (blockIdx.x * blockDim.x + threadIdx.x) >> 6;
  int lane = threadIdx.x & 63;
  if (wv >= n) return;
  float4 v = *(const float4*)&xh[(size_t)wv * 256 + 4 * lane];
  float4 a = *(const float4*)&asrc[4 * lane];
  float4 d = *(const float4*)&adst[4 * lane];
  float s = v.x * a.x + v.y * a.y + v.z * a.z + v.w * a.w;
  float t = v.x * d.x + v.y * d.y + v.z * d.z + v.w * d.w;
#pragma unroll
  for (int m = 1; m <= 8; m <<= 1) {
    s += __shfl_xor(s, m);
    t += __shfl_xor(t, m);
  }
  if ((lane & 15) == 0) {
    als[wv * 4 + (lane >> 4)] = s;
    ald[wv * 4 + (lane >> 4)] = t;
  }
}

__global__ __launch_bounds__(256) void alpha2_kernel(const float* __restrict__ xh,
                                                     const float* __restrict__ asrc,
                                                     const float* __restrict__ adst,
                                                     float* __restrict__ als,
                                                     float* __restrict__ ald, int n) {
  int wv = (blockIdx.x * blockDim.x + threadIdx.x) >> 6;
  int lane = threadIdx.x & 63;
  if (wv >= n) return;
  float v = xh[(size_t)wv * 64 + lane];
  float s = v * asrc[lane];
  float t = v * adst[lane];
#pragma unroll
  for (int m = 1; m <= 32; m <<= 1) {
    s += __shfl_xor(s, m);
    t += __shfl_xor(t, m);
  }
  if (lane == 0) {
    als[wv] = s;
    ald[wv] = t;
  }
}

// ---------------- aggregation ----------------
// Layer 1 (H=4): wave per node; lane owns channels [4*lane,4*lane+4); head = lane>>4.
// Single pass (no max-shift), unroll x4, float4 gathers. Epilogue: elu + bf16 hi/lo
// written directly into A2cat ([Ah|Al|Ah] K'-layout) for GEMM2.
__global__ __launch_bounds__(256) void agg1_kernel(const float* __restrict__ xh,
                                                   const float* __restrict__ als,
                                                   const float* __restrict__ ald,
                                                   const int* __restrict__ offsets,
                                                   const int* __restrict__ csr,
                                                   const float* __restrict__ bias,
                                                   unsigned short* __restrict__ A2cat, int n) {
  int node = (blockIdx.x * blockDim.x + threadIdx.x) >> 6;
  int lane = threadIdx.x & 63;
  if (node >= n) return;
  int h = lane >> 4;
  int beg = offsets[node], end = offsets[node + 1];
  float ad = ald[node * 4 + h];
  float den = 0.f;
  float ax = 0.f, ay = 0.f, az = 0.f, aw = 0.f;
  int e = beg;
  for (; e + 4 <= end; e += 4) {
    int s0 = csr[e], s1 = csr[e + 1], s2 = csr[e + 2], s3 = csr[e + 3];
    float a0 = als[s0 * 4 + h], a1 = als[s1 * 4 + h];
    float a2 = als[s2 * 4 + h], a3 = als[s3 * 4 + h];
    float4 x0 = *(const float4*)&xh[(size_t)s0 * 256 + 4 * lane];
    float4 x1 = *(const float4*)&xh[(size_t)s1 * 256 + 4 * lane];
    float4 x2 = *(const float4*)&xh[(size_t)s2 * 256 + 4 * lane];
    float4 x3 = *(const float4*)&xh[(size_t)s3 * 256 + 4 * lane];
    float e0 = __expf(leaky02(a0 + ad));
    float e1 = __expf(leaky02(a1 + ad));
    float e2 = __expf(leaky02(a2 + ad));
    float e3 = __expf(leaky02(a3 + ad));
    den += (e0 + e1) + (e2 + e3);
    ax += e0 * x0.x + e1 * x1.x + e2 * x2.x + e3 * x3.x;
    ay += e0 * x0.y + e1 * x1.y + e2 * x2.y + e3 * x3.y;
    az += e0 * x0.z + e1 * x1.z + e2 * x2.z + e3 * x3.z;
    aw += e0 * x0.w + e1 * x1.w + e2 * x2.w + e3 * x3.w;
  }
  for (; e < end; ++e) {
    int s = csr[e];
    float a = als[s * 4 + h];
    float4 xv = *(const float4*)&xh[(size_t)s * 256 + 4 * lane];
    float ex = __expf(leaky02(a + ad));
    den += ex;
    ax += ex * xv.x; ay += ex * xv.y; az += ex * xv.z; aw += ex * xv.w;
  }
  float inv = 1.f / (den + 1e-16f);
  float4 b = *(const float4*)&bias[4 * lane];
  float o0 = elu1(ax * inv + b.x);
  float o1 = elu1(ay * inv + b.y);
  float o2 = elu1(az * inv + b.z);
  float o3 = elu1(aw * inv + b.w);
  ushort4v hi, lo;
  hi[0] = bf16_rne(o0); lo[0] = bf16_rne(o0 - bf16_to_f(hi[0]));
  hi[1] = bf16_rne(o1); lo[1] = bf16_rne(o1 - bf16_to_f(hi[1]));
  hi[2] = bf16_rne(o2); lo[2] = bf16_rne(o2 - bf16_to_f(hi[2]));
  hi[3] = bf16_rne(o3); lo[3] = bf16_rne(o3 - bf16_to_f(hi[3]));
  size_t base = (size_t)node * 768 + 4 * lane;
  *(ushort4v*)&A2cat[base]       = hi;
  *(ushort4v*)&A2cat[base + 256] = lo;
  *(ushort4v*)&A2cat[base + 512] = hi;
}

// Layer 2 (H=1, C=64): wave per node, 4 edge-groups x 16 lanes, lane owns 4 channels.
__global__ __launch_bounds__(256) void agg2_kernel(const float* __restrict__ xh,
                                                   const float* __restrict__ als,
                                                   const float* __restrict__ ald,
                                                   const int* __restrict__ offsets,
                                                   const int* __restrict__ csr,
                                                   const float* __restrict__ bias,
                                                   float* __restrict__ out, int n) {
  int node = (blockIdx.x * blockDim.x + threadIdx.x) >> 6;
  int lane = threadIdx.x & 63;
  if (node >= n) return;
  int g = lane >> 4, li = lane & 15;
  int beg = offsets[node], end = offsets[node + 1];
  float ad = ald[node];
  float den = 0.f;
  float ax = 0.f, ay = 0.f, az = 0.f, aw = 0.f;
  for (int e0 = beg; e0 < end; e0 += 4) {
    int e = e0 + g;
    if (e < end) {
      int s = csr[e];
      float ex = __expf(leaky02(als[s] + ad));
      float4 xv = *(const float4*)&xh[(size_t)s * 64 + 4 * li];
      den += ex;
      ax += ex * xv.x; ay += ex * xv.y; az += ex * xv.z; aw += ex * xv.w;
    }
  }
#pragma unroll
  for (int m = 16; m <= 32; m <<= 1) {
    den += __shfl_xor(den, m);
    ax += __shfl_xor(ax, m);
    ay += __shfl_xor(ay, m);
    az += __shfl_xor(az, m);
    aw += __shfl_xor(aw, m);
  }
  if (g == 0) {
    float inv = 1.f / (den + 1e-16f);
    float4 b = *(const float4*)&bias[4 * li];
    float4 o;
    o.x = elu1(ax * inv + b.x);
    o.y = elu1(ay * inv + b.y);
    o.z = elu1(az * inv + b.z);
    o.w = elu1(aw * inv + b.w);
    *(float4*)&out[(size_t)node * 64 + 4 * li] = o;
  }
}

// ---------------- launch ----------------

extern "C" void kernel_launch(void* const* d_in, const int* in_sizes, int n_in,
                              void* d_out, int out_size, void* d_ws, size_t ws_size,
                              hipStream_t stream) {
  const float* x   = (const float*)d_in[0];
  const int*   ei  = (const int*)d_in[1];
  const float* W1  = (const float*)d_in[2];
  const float* as1 = (const float*)d_in[3];
  const float* ad1 = (const float*)d_in[4];
  const float* b1  = (const float*)d_in[5];
  const float* W2  = (const float*)d_in[6];
  const float* as2 = (const float*)d_in[7];
  const float* ad2 = (const float*)d_in[8];
  const float* b2  = (const float*)d_in[9];
  float* out = (float*)d_out;

  const int E = in_sizes[1] / 2;    // 800000
  const int n = in_sizes[0] / 256;  // 50000
  const int Mpad = ((n + 127) / 128) * 128;  // 50048
  const int nb = (n + 255) / 256;   // scan blocks

  size_t off = 0;
  auto alloc = [&](size_t bytes) -> void* {
    void* p = (char*)d_ws + off;
    off += (bytes + 511) & ~(size_t)511;
    return p;
  };
  unsigned short* Acat = (unsigned short*)alloc((size_t)Mpad * 768 * 2);  // also A2cat
  float* xh    = (float*)alloc((size_t)n * 256 * 4);                      // xh1; reused xh2
  unsigned short* Bt1 = (unsigned short*)alloc((size_t)256 * 768 * 2);
  unsigned short* Bt2 = (unsigned short*)alloc((size_t)64 * 768 * 2);
  float* als1v = (float*)alloc((size_t)n * 4 * 4);
  float* ald1v = (float*)alloc((size_t)n * 4 * 4);
  float* als2v = (float*)alloc((size_t)n * 4);
  float* ald2v = (float*)alloc((size_t)n * 4);
  int* count   = (int*)alloc((size_t)n * 4);
  int* cursor  = (int*)alloc((size_t)n * 4);
  int* offsets = (int*)alloc((size_t)(n + 1) * 4);
  int* locpre  = (int*)alloc((size_t)n * 4);
  int* bsum    = (int*)alloc(256 * 4);
  int* csr     = (int*)alloc((size_t)(E + n) * 4);

  const int* srcv = ei;
  const int* dstv = ei + E;

  // CSR
  hipMemsetAsync(count, 0, (size_t)n * 4, stream);
  count_kernel<<<(E + 255) / 256, 256, 0, stream>>>(dstv, count, E);
  scan1_kernel<<<nb, 256, 0, stream>>>(count, locpre, bsum, n);
  scan2_kernel<<<1, 256, 0, stream>>>(bsum, nb);
  scan3_kernel<<<nb, 256, 0, stream>>>(locpre, bsum, offsets, csr, cursor, n, E + n);
  scatter_kernel<<<(E + 255) / 256, 256, 0, stream>>>(srcv, dstv, offsets, cursor, csr, E);

  // conversions
  convB_kernel<<<(256 * 64 + 255) / 256, 256, 0, stream>>>(W1, Bt1, 256);
  convB_kernel<<<(64 * 64 + 255) / 256, 256, 0, stream>>>(W2, Bt2, 64);
  convA_kernel<<<(n * 64 + 255) / 256, 256, 0, stream>>>(x, Acat, n);

  // Layer 1
  gemm_bf16<128, 2, 2><<<dim3(Mpad / 128, 2), 256, 0, stream>>>(Acat, Bt1, xh, n, 256);
  alpha1_kernel<<<(n + 3) / 4, 256, 0, stream>>>(xh, as1, ad1, als1v, ald1v, n);
  agg1_kernel<<<(n + 3) / 4, 256, 0, stream>>>(xh, als1v, ald1v, offsets, csr, b1, Acat, n);

  // Layer 2 (A2cat aliases Acat; xh2 aliases xh)
  gemm_bf16<64, 4, 1><<<dim3(Mpad / 128, 1), 256, 0, stream>>>(Acat, Bt2, xh, n, 64);
  alpha2_kernel<<<(n + 3) / 4, 256, 0, stream>>>(xh, as2, ad2, als2v, ald2v, n);
  agg2_kernel<<<(n + 3) / 4, 256, 0, stream>>>(xh, als2v, ald2v, offsets, csr, b2, out, n);
}

// Round 5
// 396.817 us; speedup vs baseline: 1.9307x; 1.1581x over previous
//
#include <hip/hip_runtime.h>
#include <math.h>

// LegalGAT: N=50000, E=800000, F_IN=256, HID=64, HEADS=4.
// Pipeline: CSR build -> split-bf16 MFMA GEMM1 (fp16 out) -> alpha1 -> agg1 (fused bf16 hi/lo)
//           -> MFMA GEMM2 (fp16 out) -> alpha2 -> agg2.
// xh held in fp16: halves gather traffic in agg kernels (L2-miss-path bound),
// fp16 chosen over bf16 for 4x lower rounding error (2^-11 vs 2^-9).

using short8_t = __attribute__((ext_vector_type(8))) short;
using f32x4   = __attribute__((ext_vector_type(4))) float;
using ushort4v = __attribute__((ext_vector_type(4))) unsigned short;
using half4 = __attribute__((ext_vector_type(4))) _Float16;

__device__ __forceinline__ float leaky02(float t) { return t > 0.f ? t : 0.2f * t; }
__device__ __forceinline__ float elu1(float t) { return t > 0.f ? t : (__expf(t) - 1.f); }

__device__ __forceinline__ unsigned short bf16_rne(float f) {
  unsigned u = __float_as_uint(f);
  unsigned r = u + 0x7FFFu + ((u >> 16) & 1u);
  return (unsigned short)(r >> 16);
}
__device__ __forceinline__ float bf16_to_f(unsigned short h) {
  return __uint_as_float(((unsigned)h) << 16);
}

// ---------------- CSR build ----------------

__global__ __launch_bounds__(256) void count_kernel(const int* __restrict__ dst,
                                                    int* __restrict__ count, int E) {
  int e = blockIdx.x * blockDim.x + threadIdx.x;
  if (e < E) atomicAdd(&count[dst[e]], 1);
}

__global__ __launch_bounds__(256) void scan1_kernel(const int* __restrict__ count,
                                                    int* __restrict__ locpre,
                                                    int* __restrict__ bsum, int n) {
  __shared__ int sh[256];
  int t = threadIdx.x;
  int node = blockIdx.x * 256 + t;
  int v = (node < n) ? (1 + count[node]) : 0;
  sh[t] = v;
  __syncthreads();
  for (int off = 1; off < 256; off <<= 1) {
    int u = (t >= off) ? sh[t - off] : 0;
    __syncthreads();
    sh[t] += u;
    __syncthreads();
  }
  if (node < n) locpre[node] = sh[t] - v;
  if (t == 255) bsum[blockIdx.x] = sh[255];
}

__global__ __launch_bounds__(256) void scan2_kernel(int* __restrict__ bsum, int nb) {
  __shared__ int sh[256];
  int t = threadIdx.x;
  int v = (t < nb) ? bsum[t] : 0;
  sh[t] = v;
  __syncthreads();
  for (int off = 1; off < 256; off <<= 1) {
    int u = (t >= off) ? sh[t - off] : 0;
    __syncthreads();
    sh[t] += u;
    __syncthreads();
  }
  if (t < nb) bsum[t] = sh[t] - v;  // exclusive
}

__global__ __launch_bounds__(256) void scan3_kernel(const int* __restrict__ locpre,
                                                    const int* __restrict__ bsum,
                                                    int* __restrict__ offsets,
                                                    int* __restrict__ csr,
                                                    int* __restrict__ cursor,
                                                    int n, int Etot) {
  int node = blockIdx.x * 256 + threadIdx.x;
  if (node >= n) return;
  int o = bsum[blockIdx.x] + locpre[node];
  offsets[node] = o;
  csr[o] = node;  // self-loop in slot 0
  cursor[node] = 0;
  if (node == n - 1) offsets[n] = Etot;
}

__global__ __launch_bounds__(256) void scatter_kernel(const int* __restrict__ src,
                                                      const int* __restrict__ dst,
                                                      const int* __restrict__ offsets,
                                                      int* __restrict__ cursor,
                                                      int* __restrict__ csr, int E) {
  int e = blockIdx.x * blockDim.x + threadIdx.x;
  if (e < E) {
    int d = dst[e];
    int pos = atomicAdd(&cursor[d], 1);
    csr[offsets[d] + 1 + pos] = src[e];
  }
}

// ---------------- conversions to split-bf16 ----------------
// Acat row layout along K': [Ah(256) | Al(256) | Ah(256)]
__global__ __launch_bounds__(256) void convA_kernel(const float* __restrict__ X,
                                                    unsigned short* __restrict__ Acat, int M) {
  int idx = blockIdx.x * blockDim.x + threadIdx.x;
  if (idx >= M * 64) return;
  int m = idx >> 6;
  int c4 = (idx & 63) * 4;
  float4 v = *(const float4*)&X[(size_t)m * 256 + c4];
  ushort4v hi, lo;
  hi[0] = bf16_rne(v.x); lo[0] = bf16_rne(v.x - bf16_to_f(hi[0]));
  hi[1] = bf16_rne(v.y); lo[1] = bf16_rne(v.y - bf16_to_f(hi[1]));
  hi[2] = bf16_rne(v.z); lo[2] = bf16_rne(v.z - bf16_to_f(hi[2]));
  hi[3] = bf16_rne(v.w); lo[3] = bf16_rne(v.w - bf16_to_f(hi[3]));
  size_t base = (size_t)m * 768 + c4;
  *(ushort4v*)&Acat[base]       = hi;
  *(ushort4v*)&Acat[base + 256] = lo;
  *(ushort4v*)&Acat[base + 512] = hi;
}

// W [K=256][N] -> Bt [N][768] with k-layout [Bh | Bh | Bl]
__global__ __launch_bounds__(256) void convB_kernel(const float* __restrict__ W,
                                                    unsigned short* __restrict__ Bt, int N) {
  int idx = blockIdx.x * blockDim.x + threadIdx.x;
  if (idx >= N * 64) return;
  int n = idx >> 6;
  int k4 = (idx & 63) * 4;
  ushort4v hi, lo;
#pragma unroll
  for (int i = 0; i < 4; ++i) {
    float w = W[(size_t)(k4 + i) * N + n];
    hi[i] = bf16_rne(w);
    lo[i] = bf16_rne(w - bf16_to_f(hi[i]));
  }
  size_t base = (size_t)n * 768 + k4;
  *(ushort4v*)&Bt[base]       = hi;
  *(ushort4v*)&Bt[base + 256] = hi;
  *(ushort4v*)&Bt[base + 512] = lo;
}

// ---------------- bf16 MFMA GEMM: C[M,N] = Acat[M,768] * Bt[N,768]^T, fp16 out ----------------
// BM=128, BK=32, 256 threads = 4 waves (WR x WC). XOR chunk swizzle on 16B units.
template <int BN, int WR, int WC>
__global__ __launch_bounds__(256) void gemm_bf16(const unsigned short* __restrict__ A,
                                                 const unsigned short* __restrict__ Bt,
                                                 _Float16* __restrict__ C, int M, int N) {
  constexpr int BM = 128, BK = 32, KTOT = 768;
  constexpr int WM = BM / WR, WN = BN / WC;
  constexpr int MR = WM / 16, NR = WN / 16;
  constexpr int ACH = (BM * 4) / 256;  // A 16B-chunks per thread
  constexpr int BCH = (BN * 4) / 256;  // B 16B-chunks per thread
  __shared__ __align__(16) unsigned short lsA[BM * BK];
  __shared__ __align__(16) unsigned short lsB[BN * BK];
  const int tid = threadIdx.x;
  const int lane = tid & 63;
  const int w = tid >> 6;
  const int wr = w / WC, wc = w % WC;
  const int bm = blockIdx.x * BM;
  const int bn = blockIdx.y * BN;

  f32x4 acc[MR][NR];
#pragma unroll
  for (int i = 0; i < MR; ++i)
#pragma unroll
    for (int j = 0; j < NR; ++j) acc[i][j] = (f32x4){0.f, 0.f, 0.f, 0.f};

  for (int k0 = 0; k0 < KTOT; k0 += BK) {
#pragma unroll
    for (int i = 0; i < ACH; ++i) {
      int id = tid + i * 256;
      int row = id >> 2, c0 = id & 3;
      int cs = c0 ^ ((row >> 1) & 3);
      *(int4*)&lsA[row * BK + cs * 8] =
          *(const int4*)&A[(size_t)(bm + row) * KTOT + k0 + c0 * 8];
    }
#pragma unroll
    for (int i = 0; i < BCH; ++i) {
      int id = tid + i * 256;
      int row = id >> 2, c0 = id & 3;
      int cs = c0 ^ ((row >> 1) & 3);
      *(int4*)&lsB[row * BK + cs * 8] =
          *(const int4*)&Bt[(size_t)(bn + row) * KTOT + k0 + c0 * 8];
    }
    __syncthreads();
    short8_t af[MR], bf[NR];
#pragma unroll
    for (int mr = 0; mr < MR; ++mr) {
      int rr = wr * WM + mr * 16 + (lane & 15);
      int kc = (lane >> 4) ^ ((rr >> 1) & 3);
      af[mr] = *(const short8_t*)&lsA[rr * BK + kc * 8];
    }
#pragma unroll
    for (int nr = 0; nr < NR; ++nr) {
      int rn = wc * WN + nr * 16 + (lane & 15);
      int kc = (lane >> 4) ^ ((rn >> 1) & 3);
      bf[nr] = *(const short8_t*)&lsB[rn * BK + kc * 8];
    }
#pragma unroll
    for (int mr = 0; mr < MR; ++mr)
#pragma unroll
      for (int nr = 0; nr < NR; ++nr)
        acc[mr][nr] = __builtin_amdgcn_mfma_f32_16x16x32_bf16(af[mr], bf[nr], acc[mr][nr], 0, 0, 0);
    __syncthreads();
  }
#pragma unroll
  for (int mr = 0; mr < MR; ++mr) {
#pragma unroll
    for (int j = 0; j < 4; ++j) {
      int r = bm + wr * WM + mr * 16 + (lane >> 4) * 4 + j;
      if (r < M) {
#pragma unroll
        for (int nr = 0; nr < NR; ++nr) {
          int c = bn + wc * WN + nr * 16 + (lane & 15);
          C[(size_t)r * N + c] = (_Float16)acc[mr][nr][j];
        }
      }
    }
  }
}

// ---------------- alpha dot products (fp16 xh) ----------------
__global__ __launch_bounds__(256) void alpha1_kernel(const _Float16* __restrict__ xh,
                                                     const float* __restrict__ asrc,
                                                     const float* __restrict__ adst,
                                                     float* __restrict__ als,
                                                     float* __restrict__ ald, int n) {
  int wv = (blockIdx.x * blockDim.x + threadIdx.x) >> 6;
  int lane = threadIdx.x & 63;
  if (wv >= n) return;
  half4 v = *(const half4*)&xh[(size_t)wv * 256 + 4 * lane];
  float4 a = *(const float4*)&asrc[4 * lane];
  float4 d = *(const float4*)&adst[4 * lane];
  float v0 = (float)v[0], v1 = (float)v[1], v2 = (float)v[2], v3 = (float)v[3];
  float s = v0 * a.x + v1 * a.y + v2 * a.z + v3 * a.w;
  float t = v0 * d.x + v1 * d.y + v2 * d.z + v3 * d.w;
#pragma unroll
  for (int m = 1; m <= 8; m <<= 1) {
    s += __shfl_xor(s, m);
    t += __shfl_xor(t, m);
  }
  if ((lane & 15) == 0) {
    als[wv * 4 + (lane >> 4)] = s;
    ald[wv * 4 + (lane >> 4)] = t;
  }
}

__global__ __launch_bounds__(256) void alpha2_kernel(const _Float16* __restrict__ xh,
                                                     const float* __restrict__ asrc,
                                                     const float* __restrict__ adst,
                                                     float* __restrict__ als,
                                                     float* __restrict__ ald, int n) {
  int wv = (blockIdx.x * blockDim.x + threadIdx.x) >> 6;
  int lane = threadIdx.x & 63;
  if (wv >= n) return;
  float v = (float)xh[(size_t)wv * 64 + lane];
  float s = v * asrc[lane];
  float t = v * adst[lane];
#pragma unroll
  for (int m = 1; m <= 32; m <<= 1) {
    s += __shfl_xor(s, m);
    t += __shfl_xor(t, m);
  }
  if (lane == 0) {
    als[wv] = s;
    ald[wv] = t;
  }
}

// ---------------- aggregation ----------------
// Layer 1 (H=4): wave per node; lane owns channels [4*lane,4*lane+4); head = lane>>4.
// Single pass (no max-shift), unroll x4, 8B fp16 gathers. Epilogue: elu + bf16 hi/lo
// written directly into A2cat ([Ah|Al|Ah] K'-layout) for GEMM2.
__global__ __launch_bounds__(256) void agg1_kernel(const _Float16* __restrict__ xh,
                                                   const float* __restrict__ als,
                                                   const float* __restrict__ ald,
                                                   const int* __restrict__ offsets,
                                                   const int* __restrict__ csr,
                                                   const float* __restrict__ bias,
                                                   unsigned short* __restrict__ A2cat, int n) {
  int node = (blockIdx.x * blockDim.x + threadIdx.x) >> 6;
  int lane = threadIdx.x & 63;
  if (node >= n) return;
  int h = lane >> 4;
  int beg = offsets[node], end = offsets[node + 1];
  float ad = ald[node * 4 + h];
  float den = 0.f;
  float ax = 0.f, ay = 0.f, az = 0.f, aw = 0.f;
  int e = beg;
  for (; e + 4 <= end; e += 4) {
    int s0 = csr[e], s1 = csr[e + 1], s2 = csr[e + 2], s3 = csr[e + 3];
    float a0 = als[s0 * 4 + h], a1 = als[s1 * 4 + h];
    float a2 = als[s2 * 4 + h], a3 = als[s3 * 4 + h];
    half4 x0 = *(const half4*)&xh[(size_t)s0 * 256 + 4 * lane];
    half4 x1 = *(const half4*)&xh[(size_t)s1 * 256 + 4 * lane];
    half4 x2 = *(const half4*)&xh[(size_t)s2 * 256 + 4 * lane];
    half4 x3 = *(const half4*)&xh[(size_t)s3 * 256 + 4 * lane];
    float e0 = __expf(leaky02(a0 + ad));
    float e1 = __expf(leaky02(a1 + ad));
    float e2 = __expf(leaky02(a2 + ad));
    float e3 = __expf(leaky02(a3 + ad));
    den += (e0 + e1) + (e2 + e3);
    ax += e0 * (float)x0[0] + e1 * (float)x1[0] + e2 * (float)x2[0] + e3 * (float)x3[0];
    ay += e0 * (float)x0[1] + e1 * (float)x1[1] + e2 * (float)x2[1] + e3 * (float)x3[1];
    az += e0 * (float)x0[2] + e1 * (float)x1[2] + e2 * (float)x2[2] + e3 * (float)x3[2];
    aw += e0 * (float)x0[3] + e1 * (float)x1[3] + e2 * (float)x2[3] + e3 * (float)x3[3];
  }
  for (; e < end; ++e) {
    int s = csr[e];
    float a = als[s * 4 + h];
    half4 xv = *(const half4*)&xh[(size_t)s * 256 + 4 * lane];
    float ex = __expf(leaky02(a + ad));
    den += ex;
    ax += ex * (float)xv[0]; ay += ex * (float)xv[1];
    az += ex * (float)xv[2]; aw += ex * (float)xv[3];
  }
  float inv = 1.f / (den + 1e-16f);
  float4 b = *(const float4*)&bias[4 * lane];
  float o0 = elu1(ax * inv + b.x);
  float o1 = elu1(ay * inv + b.y);
  float o2 = elu1(az * inv + b.z);
  float o3 = elu1(aw * inv + b.w);
  ushort4v hi, lo;
  hi[0] = bf16_rne(o0); lo[0] = bf16_rne(o0 - bf16_to_f(hi[0]));
  hi[1] = bf16_rne(o1); lo[1] = bf16_rne(o1 - bf16_to_f(hi[1]));
  hi[2] = bf16_rne(o2); lo[2] = bf16_rne(o2 - bf16_to_f(hi[2]));
  hi[3] = bf16_rne(o3); lo[3] = bf16_rne(o3 - bf16_to_f(hi[3]));
  size_t base = (size_t)node * 768 + 4 * lane;
  *(ushort4v*)&A2cat[base]       = hi;
  *(ushort4v*)&A2cat[base + 256] = lo;
  *(ushort4v*)&A2cat[base + 512] = hi;
}

// Layer 2 (H=1, C=64): wave per node, 4 edge-groups x 16 lanes, lane owns 4 channels.
__global__ __launch_bounds__(256) void agg2_kernel(const _Float16* __restrict__ xh,
                                                   const float* __restrict__ als,
                                                   const float* __restrict__ ald,
                                                   const int* __restrict__ offsets,
                                                   const int* __restrict__ csr,
                                                   const float* __restrict__ bias,
                                                   float* __restrict__ out, int n) {
  int node = (blockIdx.x * blockDim.x + threadIdx.x) >> 6;
  int lane = threadIdx.x & 63;
  if (node >= n) return;
  int g = lane >> 4, li = lane & 15;
  int beg = offsets[node], end = offsets[node + 1];
  float ad = ald[node];
  float den = 0.f;
  float ax = 0.f, ay = 0.f, az = 0.f, aw = 0.f;
  for (int e0 = beg; e0 < end; e0 += 4) {
    int e = e0 + g;
    if (e < end) {
      int s = csr[e];
      float ex = __expf(leaky02(als[s] + ad));
      half4 xv = *(const half4*)&xh[(size_t)s * 64 + 4 * li];
      den += ex;
      ax += ex * (float)xv[0]; ay += ex * (float)xv[1];
      az += ex * (float)xv[2]; aw += ex * (float)xv[3];
    }
  }
#pragma unroll
  for (int m = 16; m <= 32; m <<= 1) {
    den += __shfl_xor(den, m);
    ax += __shfl_xor(ax, m);
    ay += __shfl_xor(ay, m);
    az += __shfl_xor(az, m);
    aw += __shfl_xor(aw, m);
  }
  if (g == 0) {
    float inv = 1.f / (den + 1e-16f);
    float4 b = *(const float4*)&bias[4 * li];
    float4 o;
    o.x = elu1(ax * inv + b.x);
    o.y = elu1(ay * inv + b.y);
    o.z = elu1(az * inv + b.z);
    o.w = elu1(aw * inv + b.w);
    *(float4*)&out[(size_t)node * 64 + 4 * li] = o;
  }
}

// ---------------- launch ----------------

extern "C" void kernel_launch(void* const* d_in, const int* in_sizes, int n_in,
                              void* d_out, int out_size, void* d_ws, size_t ws_size,
                              hipStream_t stream) {
  const float* x   = (const float*)d_in[0];
  const int*   ei  = (const int*)d_in[1];
  const float* W1  = (const float*)d_in[2];
  const float* as1 = (const float*)d_in[3];
  const float* ad1 = (const float*)d_in[4];
  const float* b1  = (const float*)d_in[5];
  const float* W2  = (const float*)d_in[6];
  const float* as2 = (const float*)d_in[7];
  const float* ad2 = (const float*)d_in[8];
  const float* b2  = (const float*)d_in[9];
  float* out = (float*)d_out;

  const int E = in_sizes[1] / 2;    // 800000
  const int n = in_sizes[0] / 256;  // 50000
  const int Mpad = ((n + 127) / 128) * 128;  // 50048
  const int nb = (n + 255) / 256;   // scan blocks

  size_t off = 0;
  auto alloc = [&](size_t bytes) -> void* {
    void* p = (char*)d_ws + off;
    off += (bytes + 511) & ~(size_t)511;
    return p;
  };
  unsigned short* Acat = (unsigned short*)alloc((size_t)Mpad * 768 * 2);  // also A2cat
  _Float16* xh = (_Float16*)alloc((size_t)n * 256 * 2);                   // xh1; reused xh2
  unsigned short* Bt1 = (unsigned short*)alloc((size_t)256 * 768 * 2);
  unsigned short* Bt2 = (unsigned short*)alloc((size_t)64 * 768 * 2);
  float* als1v = (float*)alloc((size_t)n * 4 * 4);
  float* ald1v = (float*)alloc((size_t)n * 4 * 4);
  float* als2v = (float*)alloc((size_t)n * 4);
  float* ald2v = (float*)alloc((size_t)n * 4);
  int* count   = (int*)alloc((size_t)n * 4);
  int* cursor  = (int*)alloc((size_t)n * 4);
  int* offsets = (int*)alloc((size_t)(n + 1) * 4);
  int* locpre  = (int*)alloc((size_t)n * 4);
  int* bsum    = (int*)alloc(256 * 4);
  int* csr     = (int*)alloc((size_t)(E + n) * 4);

  const int* srcv = ei;
  const int* dstv = ei + E;

  // CSR
  hipMemsetAsync(count, 0, (size_t)n * 4, stream);
  count_kernel<<<(E + 255) / 256, 256, 0, stream>>>(dstv, count, E);
  scan1_kernel<<<nb, 256, 0, stream>>>(count, locpre, bsum, n);
  scan2_kernel<<<1, 256, 0, stream>>>(bsum, nb);
  scan3_kernel<<<nb, 256, 0, stream>>>(locpre, bsum, offsets, csr, cursor, n, E + n);
  scatter_kernel<<<(E + 255) / 256, 256, 0, stream>>>(srcv, dstv, offsets, cursor, csr, E);

  // conversions
  convB_kernel<<<(256 * 64 + 255) / 256, 256, 0, stream>>>(W1, Bt1, 256);
  convB_kernel<<<(64 * 64 + 255) / 256, 256, 0, stream>>>(W2, Bt2, 64);
  convA_kernel<<<(n * 64 + 255) / 256, 256, 0, stream>>>(x, Acat, n);

  // Layer 1
  gemm_bf16<128, 2, 2><<<dim3(Mpad / 128, 2), 256, 0, stream>>>(Acat, Bt1, xh, n, 256);
  alpha1_kernel<<<(n + 3) / 4, 256, 0, stream>>>(xh, as1, ad1, als1v, ald1v, n);
  agg1_kernel<<<(n + 3) / 4, 256, 0, stream>>>(xh, als1v, ald1v, offsets, csr, b1, Acat, n);

  // Layer 2 (A2cat aliases Acat; xh2 aliases xh)
  gemm_bf16<64, 4, 1><<<dim3(Mpad / 128, 1), 256, 0, stream>>>(Acat, Bt2, xh, n, 64);
  alpha2_kernel<<<(n + 3) / 4, 256, 0, stream>>>(xh, as2, ad2, als2v, ald2v, n);
  agg2_kernel<<<(n + 3) / 4, 256, 0, stream>>>(xh, als2v, ald2v, offsets, csr, b2, out, n);
}

// Round 6
// 354.914 us; speedup vs baseline: 2.1587x; 1.1181x over previous
//
#include <hip/hip_runtime.h>
#include <math.h>

// LegalGAT: N=50000, E=800000, F_IN=256, HID=64, HEADS=4.
// Pipeline: CSR build -> fused split-bf16 MFMA GEMM1 (f32 in, fp16 out, alpha fused)
//           -> agg1 (fused bf16 hi/lo out) -> fused GEMM2 -> agg2.
// Split GEMM: C = Ah*Bh + Al*Bh + Ah*Bl with hi/lo built in-register at staging.

using short8_t  = __attribute__((ext_vector_type(8))) short;
using f32x4     = __attribute__((ext_vector_type(4))) float;
using ushort4v  = __attribute__((ext_vector_type(4))) unsigned short;
using ushort8v  = __attribute__((ext_vector_type(8))) unsigned short;
using half4     = __attribute__((ext_vector_type(4))) _Float16;

__device__ __forceinline__ float leaky02(float t) { return t > 0.f ? t : 0.2f * t; }
__device__ __forceinline__ float elu1(float t) { return t > 0.f ? t : (__expf(t) - 1.f); }

__device__ __forceinline__ unsigned short bf16_rne(float f) {
  unsigned u = __float_as_uint(f);
  unsigned r = u + 0x7FFFu + ((u >> 16) & 1u);
  return (unsigned short)(r >> 16);
}
__device__ __forceinline__ float bf16_to_f(unsigned short h) {
  return __uint_as_float(((unsigned)h) << 16);
}

// ---------------- CSR build ----------------

__global__ __launch_bounds__(256) void count_kernel(const int* __restrict__ dst,
                                                    int* __restrict__ count, int E) {
  int e = blockIdx.x * blockDim.x + threadIdx.x;
  if (e < E) atomicAdd(&count[dst[e]], 1);
}

__global__ __launch_bounds__(256) void scan1_kernel(const int* __restrict__ count,
                                                    int* __restrict__ locpre,
                                                    int* __restrict__ bsum, int n) {
  __shared__ int sh[256];
  int t = threadIdx.x;
  int node = blockIdx.x * 256 + t;
  int v = (node < n) ? (1 + count[node]) : 0;
  sh[t] = v;
  __syncthreads();
  for (int off = 1; off < 256; off <<= 1) {
    int u = (t >= off) ? sh[t - off] : 0;
    __syncthreads();
    sh[t] += u;
    __syncthreads();
  }
  if (node < n) locpre[node] = sh[t] - v;
  if (t == 255) bsum[blockIdx.x] = sh[255];
}

__global__ __launch_bounds__(256) void scan2_kernel(int* __restrict__ bsum, int nb) {
  __shared__ int sh[256];
  int t = threadIdx.x;
  int v = (t < nb) ? bsum[t] : 0;
  sh[t] = v;
  __syncthreads();
  for (int off = 1; off < 256; off <<= 1) {
    int u = (t >= off) ? sh[t - off] : 0;
    __syncthreads();
    sh[t] += u;
    __syncthreads();
  }
  if (t < nb) bsum[t] = sh[t] - v;  // exclusive
}

__global__ __launch_bounds__(256) void scan3_kernel(const int* __restrict__ locpre,
                                                    const int* __restrict__ bsum,
                                                    int* __restrict__ offsets,
                                                    int* __restrict__ csr,
                                                    int* __restrict__ cursor,
                                                    int n, int Etot) {
  int node = blockIdx.x * 256 + threadIdx.x;
  if (node >= n) return;
  int o = bsum[blockIdx.x] + locpre[node];
  offsets[node] = o;
  csr[o] = node;  // self-loop in slot 0
  cursor[node] = 0;
  if (node == n - 1) offsets[n] = Etot;
}

__global__ __launch_bounds__(256) void scatter_kernel(const int* __restrict__ src,
                                                      const int* __restrict__ dst,
                                                      const int* __restrict__ offsets,
                                                      int* __restrict__ cursor,
                                                      int* __restrict__ csr, int E) {
  int e = blockIdx.x * blockDim.x + threadIdx.x;
  if (e < E) {
    int d = dst[e];
    int pos = atomicAdd(&cursor[d], 1);
    csr[offsets[d] + 1 + pos] = src[e];
  }
}

// ---------------- W [K=256][N] -> Bth/Btl [N][256] bf16 hi/lo ----------------
__global__ __launch_bounds__(256) void convB_kernel(const float* __restrict__ W,
                                                    unsigned short* __restrict__ Bth,
                                                    unsigned short* __restrict__ Btl, int N) {
  int idx = blockIdx.x * blockDim.x + threadIdx.x;
  if (idx >= N * 64) return;
  int n = idx >> 6;
  int k4 = (idx & 63) * 4;
  ushort4v hi, lo;
#pragma unroll
  for (int i = 0; i < 4; ++i) {
    float w = W[(size_t)(k4 + i) * N + n];
    hi[i] = bf16_rne(w);
    lo[i] = bf16_rne(w - bf16_to_f(hi[i]));
  }
  size_t base = (size_t)n * 256 + k4;
  *(ushort4v*)&Bth[base] = hi;
  *(ushort4v*)&Btl[base] = lo;
}

// ---------------- fused split-bf16 MFMA GEMM + alpha ----------------
// C[M,N] = A[M,256] * Bt[N,256]^T via 3-term split; A from f32 (AF32) or
// pre-split bf16 hi/lo pair. Outputs xh (fp16) and als/ald (head dot products;
// each wave's WN=64 cols span exactly one head -> complete after 16-lane reduce).
template <int BN, int WR, int WC, int H, bool AF32>
__global__ __launch_bounds__(256) void gemm_fused(
    const float* __restrict__ Af,
    const unsigned short* __restrict__ Ah, const unsigned short* __restrict__ Al,
    const unsigned short* __restrict__ Bh, const unsigned short* __restrict__ Bl,
    const float* __restrict__ asrc, const float* __restrict__ adst,
    _Float16* __restrict__ xh, float* __restrict__ als, float* __restrict__ ald,
    int M, int N) {
  constexpr int BM = 128, BK = 32, KTOT = 256;
  constexpr int WM = BM / WR, WN = BN / WC;
  constexpr int MR = WM / 16, NR = WN / 16;
  constexpr int BROUNDS = (BN * 4) / 256;
  __shared__ __align__(16) unsigned short lsAh[BM * BK];
  __shared__ __align__(16) unsigned short lsAl[BM * BK];
  __shared__ __align__(16) unsigned short lsBh[BN * BK];
  __shared__ __align__(16) unsigned short lsBl[BN * BK];
  const int tid = threadIdx.x;
  const int lane = tid & 63;
  const int w = tid >> 6;
  const int wr = w / WC, wc = w % WC;
  const int bm = blockIdx.x * BM;
  const int bn = blockIdx.y * BN;

  f32x4 acc[MR][NR];
#pragma unroll
  for (int i = 0; i < MR; ++i)
#pragma unroll
    for (int j = 0; j < NR; ++j) acc[i][j] = (f32x4){0.f, 0.f, 0.f, 0.f};

  for (int k0 = 0; k0 < KTOT; k0 += BK) {
    // A stage: 128 rows x 32 cols, hi/lo built in-register
#pragma unroll
    for (int rnd = 0; rnd < 2; ++rnd) {
      int id = rnd * 256 + tid;
      int row = id >> 2, c0 = id & 3;
      int cs = c0 ^ ((row >> 1) & 3);
      bool ok = (bm + row) < M;
      ushort8v hi, lo;
      if (AF32) {
        float vv[8];
        if (ok) {
          float4 v0 = *(const float4*)&Af[(size_t)(bm + row) * 256 + k0 + c0 * 8];
          float4 v1 = *(const float4*)&Af[(size_t)(bm + row) * 256 + k0 + c0 * 8 + 4];
          vv[0] = v0.x; vv[1] = v0.y; vv[2] = v0.z; vv[3] = v0.w;
          vv[4] = v1.x; vv[5] = v1.y; vv[6] = v1.z; vv[7] = v1.w;
        } else {
#pragma unroll
          for (int i = 0; i < 8; ++i) vv[i] = 0.f;
        }
#pragma unroll
        for (int i = 0; i < 8; ++i) {
          hi[i] = bf16_rne(vv[i]);
          lo[i] = bf16_rne(vv[i] - bf16_to_f(hi[i]));
        }
      } else {
        if (ok) {
          hi = *(const ushort8v*)&Ah[(size_t)(bm + row) * 256 + k0 + c0 * 8];
          lo = *(const ushort8v*)&Al[(size_t)(bm + row) * 256 + k0 + c0 * 8];
        } else {
#pragma unroll
          for (int i = 0; i < 8; ++i) { hi[i] = 0; lo[i] = 0; }
        }
      }
      *(ushort8v*)&lsAh[row * BK + cs * 8] = hi;
      *(ushort8v*)&lsAl[row * BK + cs * 8] = lo;
    }
    // B stage
#pragma unroll
    for (int rnd = 0; rnd < BROUNDS; ++rnd) {
      int id = rnd * 256 + tid;
      int row = id >> 2, c0 = id & 3;
      int cs = c0 ^ ((row >> 1) & 3);
      *(ushort8v*)&lsBh[row * BK + cs * 8] =
          *(const ushort8v*)&Bh[(size_t)(bn + row) * 256 + k0 + c0 * 8];
      *(ushort8v*)&lsBl[row * BK + cs * 8] =
          *(const ushort8v*)&Bl[(size_t)(bn + row) * 256 + k0 + c0 * 8];
    }
    __syncthreads();
    short8_t afh[MR], afl[MR], bfh[NR], bfl[NR];
#pragma unroll
    for (int mr = 0; mr < MR; ++mr) {
      int rr = wr * WM + mr * 16 + (lane & 15);
      int kc = (lane >> 4) ^ ((rr >> 1) & 3);
      afh[mr] = *(const short8_t*)&lsAh[rr * BK + kc * 8];
      afl[mr] = *(const short8_t*)&lsAl[rr * BK + kc * 8];
    }
#pragma unroll
    for (int nr = 0; nr < NR; ++nr) {
      int rn = wc * WN + nr * 16 + (lane & 15);
      int kc = (lane >> 4) ^ ((rn >> 1) & 3);
      bfh[nr] = *(const short8_t*)&lsBh[rn * BK + kc * 8];
      bfl[nr] = *(const short8_t*)&lsBl[rn * BK + kc * 8];
    }
#pragma unroll
    for (int mr = 0; mr < MR; ++mr)
#pragma unroll
      for (int nr = 0; nr < NR; ++nr) {
        acc[mr][nr] = __builtin_amdgcn_mfma_f32_16x16x32_bf16(afh[mr], bfh[nr], acc[mr][nr], 0, 0, 0);
        acc[mr][nr] = __builtin_amdgcn_mfma_f32_16x16x32_bf16(afl[mr], bfh[nr], acc[mr][nr], 0, 0, 0);
        acc[mr][nr] = __builtin_amdgcn_mfma_f32_16x16x32_bf16(afh[mr], bfl[nr], acc[mr][nr], 0, 0, 0);
      }
    __syncthreads();
  }

  // epilogue: xh (fp16) + fused alpha dot products
  float as_[NR], ad_[NR];
#pragma unroll
  for (int nr = 0; nr < NR; ++nr) {
    int c = bn + wc * WN + nr * 16 + (lane & 15);
    as_[nr] = asrc[c];
    ad_[nr] = adst[c];
  }
  const int head = (bn + wc * WN) >> 6;
#pragma unroll
  for (int mr = 0; mr < MR; ++mr) {
#pragma unroll
    for (int j = 0; j < 4; ++j) {
      int r = bm + wr * WM + mr * 16 + (lane >> 4) * 4 + j;
      bool ok = r < M;
      float s = 0.f, d = 0.f;
#pragma unroll
      for (int nr = 0; nr < NR; ++nr) {
        float v = acc[mr][nr][j];
        if (ok) {
          int c = bn + wc * WN + nr * 16 + (lane & 15);
          xh[(size_t)r * N + c] = (_Float16)v;
        }
        s += v * as_[nr];
        d += v * ad_[nr];
      }
#pragma unroll
      for (int m = 1; m <= 8; m <<= 1) {
        s += __shfl_xor(s, m);
        d += __shfl_xor(d, m);
      }
      if (ok && (lane & 15) == 0) {
        als[r * H + head] = s;
        ald[r * H + head] = d;
      }
    }
  }
}

// ---------------- aggregation ----------------
// Layer 1 (H=4): wave per node; lane owns channels [4*lane,4*lane+4); head = lane>>4.
// Single pass (no max-shift), unroll x4, 8B fp16 gathers. Epilogue: elu + bf16 hi/lo
// written to A2h/A2l for GEMM2.
__global__ __launch_bounds__(256) void agg1_kernel(const _Float16* __restrict__ xh,
                                                   const float* __restrict__ als,
                                                   const float* __restrict__ ald,
                                                   const int* __restrict__ offsets,
                                                   const int* __restrict__ csr,
                                                   const float* __restrict__ bias,
                                                   unsigned short* __restrict__ A2h,
                                                   unsigned short* __restrict__ A2l, int n) {
  int node = (blockIdx.x * blockDim.x + threadIdx.x) >> 6;
  int lane = threadIdx.x & 63;
  if (node >= n) return;
  int h = lane >> 4;
  int beg = offsets[node], end = offsets[node + 1];
  float ad = ald[node * 4 + h];
  float den = 0.f;
  float ax = 0.f, ay = 0.f, az = 0.f, aw = 0.f;
  int e = beg;
  for (; e + 4 <= end; e += 4) {
    int s0 = csr[e], s1 = csr[e + 1], s2 = csr[e + 2], s3 = csr[e + 3];
    float a0 = als[s0 * 4 + h], a1 = als[s1 * 4 + h];
    float a2 = als[s2 * 4 + h], a3 = als[s3 * 4 + h];
    half4 x0 = *(const half4*)&xh[(size_t)s0 * 256 + 4 * lane];
    half4 x1 = *(const half4*)&xh[(size_t)s1 * 256 + 4 * lane];
    half4 x2 = *(const half4*)&xh[(size_t)s2 * 256 + 4 * lane];
    half4 x3 = *(const half4*)&xh[(size_t)s3 * 256 + 4 * lane];
    float e0 = __expf(leaky02(a0 + ad));
    float e1 = __expf(leaky02(a1 + ad));
    float e2 = __expf(leaky02(a2 + ad));
    float e3 = __expf(leaky02(a3 + ad));
    den += (e0 + e1) + (e2 + e3);
    ax += e0 * (float)x0[0] + e1 * (float)x1[0] + e2 * (float)x2[0] + e3 * (float)x3[0];
    ay += e0 * (float)x0[1] + e1 * (float)x1[1] + e2 * (float)x2[1] + e3 * (float)x3[1];
    az += e0 * (float)x0[2] + e1 * (float)x1[2] + e2 * (float)x2[2] + e3 * (float)x3[2];
    aw += e0 * (float)x0[3] + e1 * (float)x1[3] + e2 * (float)x2[3] + e3 * (float)x3[3];
  }
  for (; e < end; ++e) {
    int s = csr[e];
    float a = als[s * 4 + h];
    half4 xv = *(const half4*)&xh[(size_t)s * 256 + 4 * lane];
    float ex = __expf(leaky02(a + ad));
    den += ex;
    ax += ex * (float)xv[0]; ay += ex * (float)xv[1];
    az += ex * (float)xv[2]; aw += ex * (float)xv[3];
  }
  float inv = 1.f / (den + 1e-16f);
  float4 b = *(const float4*)&bias[4 * lane];
  float o0 = elu1(ax * inv + b.x);
  float o1 = elu1(ay * inv + b.y);
  float o2 = elu1(az * inv + b.z);
  float o3 = elu1(aw * inv + b.w);
  ushort4v hi, lo;
  hi[0] = bf16_rne(o0); lo[0] = bf16_rne(o0 - bf16_to_f(hi[0]));
  hi[1] = bf16_rne(o1); lo[1] = bf16_rne(o1 - bf16_to_f(hi[1]));
  hi[2] = bf16_rne(o2); lo[2] = bf16_rne(o2 - bf16_to_f(hi[2]));
  hi[3] = bf16_rne(o3); lo[3] = bf16_rne(o3 - bf16_to_f(hi[3]));
  size_t base = (size_t)node * 256 + 4 * lane;
  *(ushort4v*)&A2h[base] = hi;
  *(ushort4v*)&A2l[base] = lo;
}

// Layer 2 (H=1, C=64): wave per node, 4 edge-groups x 16 lanes, lane owns 4 channels.
__global__ __launch_bounds__(256) void agg2_kernel(const _Float16* __restrict__ xh,
                                                   const float* __restrict__ als,
                                                   const float* __restrict__ ald,
                                                   const int* __restrict__ offsets,
                                                   const int* __restrict__ csr,
                                                   const float* __restrict__ bias,
                                                   float* __restrict__ out, int n) {
  int node = (blockIdx.x * blockDim.x + threadIdx.x) >> 6;
  int lane = threadIdx.x & 63;
  if (node >= n) return;
  int g = lane >> 4, li = lane & 15;
  int beg = offsets[node], end = offsets[node + 1];
  float ad = ald[node];
  float den = 0.f;
  float ax = 0.f, ay = 0.f, az = 0.f, aw = 0.f;
  for (int e0 = beg; e0 < end; e0 += 4) {
    int e = e0 + g;
    if (e < end) {
      int s = csr[e];
      float ex = __expf(leaky02(als[s] + ad));
      half4 xv = *(const half4*)&xh[(size_t)s * 64 + 4 * li];
      den += ex;
      ax += ex * (float)xv[0]; ay += ex * (float)xv[1];
      az += ex * (float)xv[2]; aw += ex * (float)xv[3];
    }
  }
#pragma unroll
  for (int m = 16; m <= 32; m <<= 1) {
    den += __shfl_xor(den, m);
    ax += __shfl_xor(ax, m);
    ay += __shfl_xor(ay, m);
    az += __shfl_xor(az, m);
    aw += __shfl_xor(aw, m);
  }
  if (g == 0) {
    float inv = 1.f / (den + 1e-16f);
    float4 b = *(const float4*)&bias[4 * li];
    float4 o;
    o.x = elu1(ax * inv + b.x);
    o.y = elu1(ay * inv + b.y);
    o.z = elu1(az * inv + b.z);
    o.w = elu1(aw * inv + b.w);
    *(float4*)&out[(size_t)node * 64 + 4 * li] = o;
  }
}

// ---------------- launch ----------------

extern "C" void kernel_launch(void* const* d_in, const int* in_sizes, int n_in,
                              void* d_out, int out_size, void* d_ws, size_t ws_size,
                              hipStream_t stream) {
  const float* x   = (const float*)d_in[0];
  const int*   ei  = (const int*)d_in[1];
  const float* W1  = (const float*)d_in[2];
  const float* as1 = (const float*)d_in[3];
  const float* ad1 = (const float*)d_in[4];
  const float* b1  = (const float*)d_in[5];
  const float* W2  = (const float*)d_in[6];
  const float* as2 = (const float*)d_in[7];
  const float* ad2 = (const float*)d_in[8];
  const float* b2  = (const float*)d_in[9];
  float* out = (float*)d_out;

  const int E = in_sizes[1] / 2;    // 800000
  const int n = in_sizes[0] / 256;  // 50000
  const int Mpad = ((n + 127) / 128) * 128;  // 50048
  const int nb = (n + 255) / 256;   // scan blocks

  size_t off = 0;
  auto alloc = [&](size_t bytes) -> void* {
    void* p = (char*)d_ws + off;
    off += (bytes + 511) & ~(size_t)511;
    return p;
  };
  _Float16* xh = (_Float16*)alloc((size_t)n * 256 * 2);        // xh1; reused xh2
  unsigned short* A2h = (unsigned short*)alloc((size_t)Mpad * 256 * 2);
  unsigned short* A2l = (unsigned short*)alloc((size_t)Mpad * 256 * 2);
  unsigned short* Bh1 = (unsigned short*)alloc((size_t)256 * 256 * 2);
  unsigned short* Bl1 = (unsigned short*)alloc((size_t)256 * 256 * 2);
  unsigned short* Bh2 = (unsigned short*)alloc((size_t)64 * 256 * 2);
  unsigned short* Bl2 = (unsigned short*)alloc((size_t)64 * 256 * 2);
  float* als1v = (float*)alloc((size_t)n * 4 * 4);
  float* ald1v = (float*)alloc((size_t)n * 4 * 4);
  float* als2v = (float*)alloc((size_t)n * 4);
  float* ald2v = (float*)alloc((size_t)n * 4);
  int* count   = (int*)alloc((size_t)n * 4);
  int* cursor  = (int*)alloc((size_t)n * 4);
  int* offsets = (int*)alloc((size_t)(n + 1) * 4);
  int* locpre  = (int*)alloc((size_t)n * 4);
  int* bsum    = (int*)alloc(256 * 4);
  int* csr     = (int*)alloc((size_t)(E + n) * 4);

  const int* srcv = ei;
  const int* dstv = ei + E;

  // CSR
  hipMemsetAsync(count, 0, (size_t)n * 4, stream);
  count_kernel<<<(E + 255) / 256, 256, 0, stream>>>(dstv, count, E);
  scan1_kernel<<<nb, 256, 0, stream>>>(count, locpre, bsum, n);
  scan2_kernel<<<1, 256, 0, stream>>>(bsum, nb);
  scan3_kernel<<<nb, 256, 0, stream>>>(locpre, bsum, offsets, csr, cursor, n, E + n);
  scatter_kernel<<<(E + 255) / 256, 256, 0, stream>>>(srcv, dstv, offsets, cursor, csr, E);

  // weight conversions
  convB_kernel<<<(256 * 64 + 255) / 256, 256, 0, stream>>>(W1, Bh1, Bl1, 256);
  convB_kernel<<<(64 * 64 + 255) / 256, 256, 0, stream>>>(W2, Bh2, Bl2, 64);

  // Layer 1: x (f32) -> xh1 + als1/ald1
  gemm_fused<128, 2, 2, 4, true><<<dim3(Mpad / 128, 2), 256, 0, stream>>>(
      x, nullptr, nullptr, Bh1, Bl1, as1, ad1, xh, als1v, ald1v, n, 256);
  agg1_kernel<<<(n + 3) / 4, 256, 0, stream>>>(xh, als1v, ald1v, offsets, csr, b1, A2h, A2l, n);

  // Layer 2: A2h/A2l (bf16) -> xh2 + als2/ald2  (xh2 aliases xh)
  gemm_fused<64, 4, 1, 1, false><<<dim3(Mpad / 128, 1), 256, 0, stream>>>(
      nullptr, A2h, A2l, Bh2, Bl2, as2, ad2, xh, als2v, ald2v, n, 64);
  agg2_kernel<<<(n + 3) / 4, 256, 0, stream>>>(xh, als2v, ald2v, offsets, csr, b2, out, n);
}

// Round 10
// 338.829 us; speedup vs baseline: 2.2612x; 1.0475x over previous
//
#include <hip/hip_runtime.h>
#include <math.h>

// LegalGAT: N=50000, E=800000, F_IN=256, HID=64, HEADS=4.
// CSR (4-padded segments w/ sentinel) -> gemm1 (split-bf16 3-term, BN=256, alpha fused)
// -> agg1 (fp16 out) -> gemm2 (fp16 1-term, alpha fused) -> agg2.

using short8_t  = __attribute__((ext_vector_type(8))) short;
using half8_t   = __attribute__((ext_vector_type(8))) _Float16;
using f32x4     = __attribute__((ext_vector_type(4))) float;
using ushort4v  = __attribute__((ext_vector_type(4))) unsigned short;
using ushort8v  = __attribute__((ext_vector_type(8))) unsigned short;
using half4     = __attribute__((ext_vector_type(4))) _Float16;

__device__ __forceinline__ float leaky02(float t) { return t > 0.f ? t : 0.2f * t; }
__device__ __forceinline__ float elu1(float t) { return t > 0.f ? t : (__expf(t) - 1.f); }

__device__ __forceinline__ unsigned short bf16_rne(float f) {
  unsigned u = __float_as_uint(f);
  unsigned r = u + 0x7FFFu + ((u >> 16) & 1u);
  return (unsigned short)(r >> 16);
}
__device__ __forceinline__ float bf16_to_f(unsigned short h) {
  return __uint_as_float(((unsigned)h) << 16);
}

// ---------------- CSR build (segments padded to x4 with sentinel src = n) ----------------

__global__ __launch_bounds__(256) void count_kernel(const int* __restrict__ dst,
                                                    int* __restrict__ count, int E) {
  int e = blockIdx.x * blockDim.x + threadIdx.x;
  if (e < E) atomicAdd(&count[dst[e]], 1);
}

__global__ __launch_bounds__(256) void scan1_kernel(const int* __restrict__ count,
                                                    int* __restrict__ locpre,
                                                    int* __restrict__ bsum, int n) {
  __shared__ int sh[256];
  int t = threadIdx.x;
  int node = blockIdx.x * 256 + t;
  int v = (node < n) ? ((count[node] + 4) & ~3) : 0;  // padded seg len
  sh[t] = v;
  __syncthreads();
  for (int off = 1; off < 256; off <<= 1) {
    int u = (t >= off) ? sh[t - off] : 0;
    __syncthreads();
    sh[t] += u;
    __syncthreads();
  }
  if (node < n) locpre[node] = sh[t] - v;
  if (t == 255) bsum[blockIdx.x] = sh[255];
}

__global__ __launch_bounds__(256) void scan2_kernel(int* __restrict__ bsum, int nb) {
  __shared__ int sh[256];
  int t = threadIdx.x;
  int v = (t < nb) ? bsum[t] : 0;
  sh[t] = v;
  __syncthreads();
  for (int off = 1; off < 256; off <<= 1) {
    int u = (t >= off) ? sh[t - off] : 0;
    __syncthreads();
    sh[t] += u;
    __syncthreads();
  }
  if (t < nb) bsum[t] = sh[t] - v;  // exclusive
}

__global__ __launch_bounds__(256) void scan3_kernel(const int* __restrict__ count,
                                                    const int* __restrict__ locpre,
                                                    const int* __restrict__ bsum,
                                                    int* __restrict__ offsets,
                                                    int* __restrict__ csr,
                                                    int* __restrict__ cursor,
                                                    float* __restrict__ als1s,  // &als1[n*4]
                                                    float* __restrict__ als2s,  // &als2[n]
                                                    int n) {
  int node = blockIdx.x * 256 + threadIdx.x;
  if (node >= n) return;
  int o = bsum[blockIdx.x] + locpre[node];
  int cnt = count[node];
  int padlen = (cnt + 4) & ~3;
  offsets[node] = o;
  csr[o] = node;  // self-loop in slot 0
  for (int p = 1 + cnt; p < padlen; ++p) csr[o + p] = n;  // sentinel fill
  cursor[node] = 0;
  if (node == n - 1) offsets[n] = o + padlen;
  if (node == 0) {
    als1s[0] = -1e30f; als1s[1] = -1e30f; als1s[2] = -1e30f; als1s[3] = -1e30f;
    als2s[0] = -1e30f;
  }
}

__global__ __launch_bounds__(256) void scatter_kernel(const int* __restrict__ src,
                                                      const int* __restrict__ dst,
                                                      const int* __restrict__ offsets,
                                                      int* __restrict__ cursor,
                                                      int* __restrict__ csr, int E) {
  int e = blockIdx.x * blockDim.x + threadIdx.x;
  if (e < E) {
    int d = dst[e];
    int pos = atomicAdd(&cursor[d], 1);
    csr[offsets[d] + 1 + pos] = src[e];
  }
}

// ---------------- weight conversions ----------------
// W1 [256][256] f32 -> Bh/Bl [256][256] bf16 hi/lo (transposed)
__global__ __launch_bounds__(256) void convB_kernel(const float* __restrict__ W,
                                                    unsigned short* __restrict__ Bth,
                                                    unsigned short* __restrict__ Btl, int N) {
  int idx = blockIdx.x * blockDim.x + threadIdx.x;
  if (idx >= N * 64) return;
  int n = idx >> 6;
  int k4 = (idx & 63) * 4;
  ushort4v hi, lo;
#pragma unroll
  for (int i = 0; i < 4; ++i) {
    float w = W[(size_t)(k4 + i) * N + n];
    hi[i] = bf16_rne(w);
    lo[i] = bf16_rne(w - bf16_to_f(hi[i]));
  }
  size_t base = (size_t)n * 256 + k4;
  *(ushort4v*)&Bth[base] = hi;
  *(ushort4v*)&Btl[base] = lo;
}

// W2 [256][64] f32 -> Bt2 [64][256] fp16 (transposed)
__global__ __launch_bounds__(256) void convB2_kernel(const float* __restrict__ W,
                                                     _Float16* __restrict__ Bt, int N) {
  int idx = blockIdx.x * blockDim.x + threadIdx.x;
  if (idx >= N * 64) return;
  int n = idx >> 6;
  int k4 = (idx & 63) * 4;
  half4 v;
#pragma unroll
  for (int i = 0; i < 4; ++i) v[i] = (_Float16)W[(size_t)(k4 + i) * N + n];
  *(half4*)&Bt[(size_t)n * 256 + k4] = v;
}

// ---------------- GEMM1: xh1 = x @ W1 (split-bf16, 3-term) + fused alpha ----------------
// BM=128, BN=256 (full N), BK=32, 512 threads = 8 waves (2x4). Each wave: WM=64, WN=64
// -> exactly one head (head = wc). A (f32) hi/lo built in-register at staging.
__global__ __launch_bounds__(512) void gemm1_fused(
    const float* __restrict__ Af,
    const unsigned short* __restrict__ Bh, const unsigned short* __restrict__ Bl,
    const float* __restrict__ asrc, const float* __restrict__ adst,
    _Float16* __restrict__ xh, float* __restrict__ als, float* __restrict__ ald, int M) {
  constexpr int BM = 128, BK = 32, KTOT = 256, NW = 256;
  constexpr int MR = 4, NR = 4;
  __shared__ __align__(16) unsigned short lsAh[BM * BK];
  __shared__ __align__(16) unsigned short lsAl[BM * BK];
  __shared__ __align__(16) unsigned short lsBh[NW * BK];
  __shared__ __align__(16) unsigned short lsBl[NW * BK];
  const int tid = threadIdx.x;
  const int lane = tid & 63;
  const int w = tid >> 6;
  const int wr = w >> 2, wc = w & 3;
  const int bm = blockIdx.x * BM;

  f32x4 acc[MR][NR];
#pragma unroll
  for (int i = 0; i < MR; ++i)
#pragma unroll
    for (int j = 0; j < NR; ++j) acc[i][j] = (f32x4){0.f, 0.f, 0.f, 0.f};

  for (int k0 = 0; k0 < KTOT; k0 += BK) {
    // A stage: 128x32, one round (512 threads x 8 elems)
    {
      int row = tid >> 2, c0 = tid & 3;
      int cs = c0 ^ ((row >> 1) & 3);
      float vv[8];
      if (bm + row < M) {
        float4 v0 = *(const float4*)&Af[(size_t)(bm + row) * 256 + k0 + c0 * 8];
        float4 v1 = *(const float4*)&Af[(size_t)(bm + row) * 256 + k0 + c0 * 8 + 4];
        vv[0] = v0.x; vv[1] = v0.y; vv[2] = v0.z; vv[3] = v0.w;
        vv[4] = v1.x; vv[5] = v1.y; vv[6] = v1.z; vv[7] = v1.w;
      } else {
#pragma unroll
        for (int i = 0; i < 8; ++i) vv[i] = 0.f;
      }
      ushort8v hi, lo;
#pragma unroll
      for (int i = 0; i < 8; ++i) {
        hi[i] = bf16_rne(vv[i]);
        lo[i] = bf16_rne(vv[i] - bf16_to_f(hi[i]));
      }
      *(ushort8v*)&lsAh[row * BK + cs * 8] = hi;
      *(ushort8v*)&lsAl[row * BK + cs * 8] = lo;
    }
    // B stage: 256x32, two rounds
#pragma unroll
    for (int rnd = 0; rnd < 2; ++rnd) {
      int id = rnd * 512 + tid;
      int row = id >> 2, c0 = id & 3;
      int cs = c0 ^ ((row >> 1) & 3);
      *(ushort8v*)&lsBh[row * BK + cs * 8] =
          *(const ushort8v*)&Bh[(size_t)row * 256 + k0 + c0 * 8];
      *(ushort8v*)&lsBl[row * BK + cs * 8] =
          *(const ushort8v*)&Bl[(size_t)row * 256 + k0 + c0 * 8];
    }
    __syncthreads();
    short8_t afh[MR], afl[MR];
#pragma unroll
    for (int mr = 0; mr < MR; ++mr) {
      int rr = wr * 64 + mr * 16 + (lane & 15);
      int kc = (lane >> 4) ^ ((rr >> 1) & 3);
      afh[mr] = *(const short8_t*)&lsAh[rr * BK + kc * 8];
      afl[mr] = *(const short8_t*)&lsAl[rr * BK + kc * 8];
    }
#pragma unroll
    for (int nr = 0; nr < NR; ++nr) {
      int rn = wc * 64 + nr * 16 + (lane & 15);
      int kc = (lane >> 4) ^ ((rn >> 1) & 3);
      short8_t bh = *(const short8_t*)&lsBh[rn * BK + kc * 8];
      short8_t bl = *(const short8_t*)&lsBl[rn * BK + kc * 8];
#pragma unroll
      for (int mr = 0; mr < MR; ++mr) {
        acc[mr][nr] = __builtin_amdgcn_mfma_f32_16x16x32_bf16(afh[mr], bh, acc[mr][nr], 0, 0, 0);
        acc[mr][nr] = __builtin_amdgcn_mfma_f32_16x16x32_bf16(afl[mr], bh, acc[mr][nr], 0, 0, 0);
        acc[mr][nr] = __builtin_amdgcn_mfma_f32_16x16x32_bf16(afh[mr], bl, acc[mr][nr], 0, 0, 0);
      }
    }
    __syncthreads();
  }

  // epilogue: xh (fp16) + per-head alpha dots (head = wc)
  float as_[NR], ad_[NR];
#pragma unroll
  for (int nr = 0; nr < NR; ++nr) {
    int c = wc * 64 + nr * 16 + (lane & 15);
    as_[nr] = asrc[c];
    ad_[nr] = adst[c];
  }
#pragma unroll
  for (int mr = 0; mr < MR; ++mr) {
#pragma unroll
    for (int j = 0; j < 4; ++j) {
      int r = bm + wr * 64 + mr * 16 + (lane >> 4) * 4 + j;
      bool ok = r < M;
      float s = 0.f, d = 0.f;
#pragma unroll
      for (int nr = 0; nr < NR; ++nr) {
        float v = acc[mr][nr][j];
        if (ok) xh[(size_t)r * 256 + wc * 64 + nr * 16 + (lane & 15)] = (_Float16)v;
        s += v * as_[nr];
        d += v * ad_[nr];
      }
#pragma unroll
      for (int m = 1; m <= 8; m <<= 1) {
        s += __shfl_xor(s, m);
        d += __shfl_xor(d, m);
      }
      if (ok && (lane & 15) == 0) {
        als[r * 4 + wc] = s;
        ald[r * 4 + wc] = d;
      }
    }
  }
}

// ---------------- GEMM2: xh2 = A2 @ W2 (fp16 1-term) + fused alpha (H=1) ----------------
// BM=128, BN=64, BK=32, 256 threads = 4 waves (4x1): WM=32, WN=64.
__global__ __launch_bounds__(256) void gemm2_fused(
    const _Float16* __restrict__ A,
    const _Float16* __restrict__ Bt,
    const float* __restrict__ asrc, const float* __restrict__ adst,
    _Float16* __restrict__ xh, float* __restrict__ als, float* __restrict__ ald, int M) {
  constexpr int BM = 128, BK = 32, KTOT = 256, NW = 64;
  constexpr int MR = 2, NR = 4;
  __shared__ __align__(16) _Float16 lsA[BM * BK];
  __shared__ __align__(16) _Float16 lsB[NW * BK];
  const int tid = threadIdx.x;
  const int lane = tid & 63;
  const int wr = tid >> 6;
  const int bm = blockIdx.x * BM;

  f32x4 acc[MR][NR];
#pragma unroll
  for (int i = 0; i < MR; ++i)
#pragma unroll
    for (int j = 0; j < NR; ++j) acc[i][j] = (f32x4){0.f, 0.f, 0.f, 0.f};

  for (int k0 = 0; k0 < KTOT; k0 += BK) {
#pragma unroll
    for (int rnd = 0; rnd < 2; ++rnd) {
      int id = rnd * 256 + tid;
      int row = id >> 2, c0 = id & 3;
      int cs = c0 ^ ((row >> 1) & 3);
      *(half8_t*)&lsA[row * BK + cs * 8] =
          *(const half8_t*)&A[(size_t)(bm + row) * 256 + k0 + c0 * 8];
    }
    {
      int row = tid >> 2, c0 = tid & 3;
      int cs = c0 ^ ((row >> 1) & 3);
      *(half8_t*)&lsB[row * BK + cs * 8] =
          *(const half8_t*)&Bt[(size_t)row * 256 + k0 + c0 * 8];
    }
    __syncthreads();
    half8_t af[MR], bf[NR];
#pragma unroll
    for (int mr = 0; mr < MR; ++mr) {
      int rr = wr * 32 + mr * 16 + (lane & 15);
      int kc = (lane >> 4) ^ ((rr >> 1) & 3);
      af[mr] = *(const half8_t*)&lsA[rr * BK + kc * 8];
    }
#pragma unroll
    for (int nr = 0; nr < NR; ++nr) {
      int rn = nr * 16 + (lane & 15);
      int kc = (lane >> 4) ^ ((rn >> 1) & 3);
      bf[nr] = *(const half8_t*)&lsB[rn * BK + kc * 8];
    }
    __syncthreads();
#pragma unroll
    for (int mr = 0; mr < MR; ++mr)
#pragma unroll
      for (int nr = 0; nr < NR; ++nr)
        acc[mr][nr] = __builtin_amdgcn_mfma_f32_16x16x32_f16(af[mr], bf[nr], acc[mr][nr], 0, 0, 0);
  }

  float as_[NR], ad_[NR];
#pragma unroll
  for (int nr = 0; nr < NR; ++nr) {
    int c = nr * 16 + (lane & 15);
    as_[nr] = asrc[c];
    ad_[nr] = adst[c];
  }
#pragma unroll
  for (int mr = 0; mr < MR; ++mr) {
#pragma unroll
    for (int j = 0; j < 4; ++j) {
      int r = bm + wr * 32 + mr * 16 + (lane >> 4) * 4 + j;
      bool ok = r < M;
      float s = 0.f, d = 0.f;
#pragma unroll
      for (int nr = 0; nr < NR; ++nr) {
        float v = acc[mr][nr][j];
        if (ok) xh[(size_t)r * 64 + nr * 16 + (lane & 15)] = (_Float16)v;
        s += v * as_[nr];
        d += v * ad_[nr];
      }
#pragma unroll
      for (int m = 1; m <= 8; m <<= 1) {
        s += __shfl_xor(s, m);
        d += __shfl_xor(d, m);
      }
      if (ok && (lane & 15) == 0) {
        als[r] = s;
        ald[r] = d;
      }
    }
  }
}

// ---------------- aggregation ----------------
// Layer 1 (H=4): wave per node; lane owns 4 channels; head = lane>>4. Branch-free
// 4-unrolled loop (padded CSR), int4 csr loads. Epilogue: elu -> fp16 A2.
__global__ __launch_bounds__(256) void agg1_kernel(const _Float16* __restrict__ xh,
                                                   const float* __restrict__ als,
                                                   const float* __restrict__ ald,
                                                   const int* __restrict__ offsets,
                                                   const int* __restrict__ csr,
                                                   const float* __restrict__ bias,
                                                   _Float16* __restrict__ A2, int n) {
  int node = (blockIdx.x * blockDim.x + threadIdx.x) >> 6;
  int lane = threadIdx.x & 63;
  if (node >= n) return;
  int h = lane >> 4;
  int beg = offsets[node], end = offsets[node + 1];
  float ad = ald[node * 4 + h];
  float den = 0.f;
  float ax = 0.f, ay = 0.f, az = 0.f, aw = 0.f;
  for (int e = beg; e < end; e += 4) {
    int4 s4 = *(const int4*)&csr[e];
    float a0 = als[s4.x * 4 + h], a1 = als[s4.y * 4 + h];
    float a2 = als[s4.z * 4 + h], a3 = als[s4.w * 4 + h];
    half4 x0 = *(const half4*)&xh[(size_t)s4.x * 256 + 4 * lane];
    half4 x1 = *(const half4*)&xh[(size_t)s4.y * 256 + 4 * lane];
    half4 x2 = *(const half4*)&xh[(size_t)s4.z * 256 + 4 * lane];
    half4 x3 = *(const half4*)&xh[(size_t)s4.w * 256 + 4 * lane];
    float e0 = __expf(leaky02(a0 + ad));
    float e1 = __expf(leaky02(a1 + ad));
    float e2 = __expf(leaky02(a2 + ad));
    float e3 = __expf(leaky02(a3 + ad));
    den += (e0 + e1) + (e2 + e3);
    ax += e0 * (float)x0[0] + e1 * (float)x1[0] + e2 * (float)x2[0] + e3 * (float)x3[0];
    ay += e0 * (float)x0[1] + e1 * (float)x1[1] + e2 * (float)x2[1] + e3 * (float)x3[1];
    az += e0 * (float)x0[2] + e1 * (float)x1[2] + e2 * (float)x2[2] + e3 * (float)x3[2];
    aw += e0 * (float)x0[3] + e1 * (float)x1[3] + e2 * (float)x2[3] + e3 * (float)x3[3];
  }
  float inv = 1.f / (den + 1e-16f);
  float4 b = *(const float4*)&bias[4 * lane];
  half4 o;
  o[0] = (_Float16)elu1(ax * inv + b.x);
  o[1] = (_Float16)elu1(ay * inv + b.y);
  o[2] = (_Float16)elu1(az * inv + b.z);
  o[3] = (_Float16)elu1(aw * inv + b.w);
  *(half4*)&A2[(size_t)node * 256 + 4 * lane] = o;
}

// Layer 2 (H=1, C=64): wave per node, 4 edge-groups x 16 lanes, branch-free.
__global__ __launch_bounds__(256) void agg2_kernel(const _Float16* __restrict__ xh,
                                                   const float* __restrict__ als,
                                                   const float* __restrict__ ald,
                                                   const int* __restrict__ offsets,
                                                   const int* __restrict__ csr,
                                                   const float* __restrict__ bias,
                                                   float* __restrict__ out, int n) {
  int node = (blockIdx.x * blockDim.x + threadIdx.x) >> 6;
  int lane = threadIdx.x & 63;
  if (node >= n) return;
  int g = lane >> 4, li = lane & 15;
  int beg = offsets[node], end = offsets[node + 1];
  float ad = ald[node];
  float den = 0.f;
  float ax = 0.f, ay = 0.f, az = 0.f, aw = 0.f;
  for (int e0 = beg; e0 < end; e0 += 4) {
    int s = csr[e0 + g];
    float ex = __expf(leaky02(als[s] + ad));
    half4 xv = *(const half4*)&xh[(size_t)s * 64 + 4 * li];
    den += ex;
    ax += ex * (float)xv[0]; ay += ex * (float)xv[1];
    az += ex * (float)xv[2]; aw += ex * (float)xv[3];
  }
#pragma unroll
  for (int m = 16; m <= 32; m <<= 1) {
    den += __shfl_xor(den, m);
    ax += __shfl_xor(ax, m);
    ay += __shfl_xor(ay, m);
    az += __shfl_xor(az, m);
    aw += __shfl_xor(aw, m);
  }
  if (g == 0) {
    float inv = 1.f / (den + 1e-16f);
    float4 b = *(const float4*)&bias[4 * li];
    float4 o;
    o.x = elu1(ax * inv + b.x);
    o.y = elu1(ay * inv + b.y);
    o.z = elu1(az * inv + b.z);
    o.w = elu1(aw * inv + b.w);
    *(float4*)&out[(size_t)node * 64 + 4 * li] = o;
  }
}

// ---------------- launch ----------------

extern "C" void kernel_launch(void* const* d_in, const int* in_sizes, int n_in,
                              void* d_out, int out_size, void* d_ws, size_t ws_size,
                              hipStream_t stream) {
  const float* x   = (const float*)d_in[0];
  const int*   ei  = (const int*)d_in[1];
  const float* W1  = (const float*)d_in[2];
  const float* as1 = (const float*)d_in[3];
  const float* ad1 = (const float*)d_in[4];
  const float* b1  = (const float*)d_in[5];
  const float* W2  = (const float*)d_in[6];
  const float* as2 = (const float*)d_in[7];
  const float* ad2 = (const float*)d_in[8];
  const float* b2  = (const float*)d_in[9];
  float* out = (float*)d_out;

  const int E = in_sizes[1] / 2;    // 800000
  const int n = in_sizes[0] / 256;  // 50000
  const int Mpad = ((n + 127) / 128) * 128;  // 50048
  const int nb = (n + 255) / 256;   // scan blocks

  size_t off = 0;
  auto alloc = [&](size_t bytes) -> void* {
    void* p = (char*)d_ws + off;
    off += (bytes + 511) & ~(size_t)511;
    return p;
  };
  _Float16* xh  = (_Float16*)alloc((size_t)(n + 1) * 256 * 2);  // xh1 (+sentinel row); reused xh2
  _Float16* A2  = (_Float16*)alloc((size_t)Mpad * 256 * 2);     // layer-1 output, fp16
  unsigned short* Bh1 = (unsigned short*)alloc((size_t)256 * 256 * 2);
  unsigned short* Bl1 = (unsigned short*)alloc((size_t)256 * 256 * 2);
  _Float16* Bt2 = (_Float16*)alloc((size_t)64 * 256 * 2);
  float* als1v = (float*)alloc((size_t)(n + 1) * 4 * 4);
  float* ald1v = (float*)alloc((size_t)n * 4 * 4);
  float* als2v = (float*)alloc((size_t)(n + 1) * 4);
  float* ald2v = (float*)alloc((size_t)n * 4);
  int* count   = (int*)alloc((size_t)n * 4);
  int* cursor  = (int*)alloc((size_t)n * 4);
  int* offsets = (int*)alloc((size_t)(n + 1) * 4);
  int* locpre  = (int*)alloc((size_t)n * 4);
  int* bsum    = (int*)alloc(256 * 4);
  int* csr     = (int*)alloc((size_t)(E + 4 * n) * 4);

  const int* srcv = ei;
  const int* dstv = ei + E;

  // CSR (padded segments)
  hipMemsetAsync(count, 0, (size_t)n * 4, stream);
  count_kernel<<<(E + 255) / 256, 256, 0, stream>>>(dstv, count, E);
  scan1_kernel<<<nb, 256, 0, stream>>>(count, locpre, bsum, n);
  scan2_kernel<<<1, 256, 0, stream>>>(bsum, nb);
  scan3_kernel<<<nb, 256, 0, stream>>>(count, locpre, bsum, offsets, csr, cursor,
                                       als1v + (size_t)n * 4, als2v + n, n);
  scatter_kernel<<<(E + 255) / 256, 256, 0, stream>>>(srcv, dstv, offsets, cursor, csr, E);

  // weight conversions
  convB_kernel<<<(256 * 64 + 255) / 256, 256, 0, stream>>>(W1, Bh1, Bl1, 256);
  convB2_kernel<<<(64 * 64 + 255) / 256, 256, 0, stream>>>(W2, Bt2, 64);

  // Layer 1
  gemm1_fused<<<Mpad / 128, 512, 0, stream>>>(x, Bh1, Bl1, as1, ad1, xh, als1v, ald1v, n);
  agg1_kernel<<<(n + 3) / 4, 256, 0, stream>>>(xh, als1v, ald1v, offsets, csr, b1, A2, n);

  // Layer 2 (xh2 aliases xh)
  gemm2_fused<<<Mpad / 128, 256, 0, stream>>>(A2, Bt2, as2, ad2, xh, als2v, ald2v, n);
  agg2_kernel<<<(n + 3) / 4, 256, 0, stream>>>(xh, als2v, ald2v, offsets, csr, b2, out, n);
}

// Round 13
// 310.703 us; speedup vs baseline: 2.4658x; 1.0905x over previous
//
#include <hip/hip_runtime.h>
#include <math.h>

// LegalGAT: N=50000, E=800000, F_IN=256, HID=64, HEADS=4.
// CSR (4-padded + sentinel) -> gemm1 (fp16 MFMA, alpha fused) -> agg1 (8-edge unrolled)
// -> gemm2 (fp16, alpha fused) -> agg2 (2x unrolled).
// fp16 1-term gemm1: err ~6e-4 on xh, same order as split-bf16 2-term at 1/3 the MFMA.

using half8_t   = __attribute__((ext_vector_type(8))) _Float16;
using f32x4     = __attribute__((ext_vector_type(4))) float;
using half4     = __attribute__((ext_vector_type(4))) _Float16;

__device__ __forceinline__ float leaky02(float t) { return t > 0.f ? t : 0.2f * t; }
__device__ __forceinline__ float elu1(float t) { return t > 0.f ? t : (__expf(t) - 1.f); }

// ---------------- CSR build (segments padded to x4 with sentinel src = n) ----------------

__global__ __launch_bounds__(256) void count_kernel(const int* __restrict__ dst,
                                                    int* __restrict__ count, int E) {
  int e = blockIdx.x * blockDim.x + threadIdx.x;
  if (e < E) atomicAdd(&count[dst[e]], 1);
}

__global__ __launch_bounds__(256) void scan1_kernel(const int* __restrict__ count,
                                                    int* __restrict__ locpre,
                                                    int* __restrict__ bsum, int n) {
  __shared__ int sh[256];
  int t = threadIdx.x;
  int node = blockIdx.x * 256 + t;
  int v = (node < n) ? ((count[node] + 4) & ~3) : 0;  // padded seg len
  sh[t] = v;
  __syncthreads();
  for (int off = 1; off < 256; off <<= 1) {
    int u = (t >= off) ? sh[t - off] : 0;
    __syncthreads();
    sh[t] += u;
    __syncthreads();
  }
  if (node < n) locpre[node] = sh[t] - v;
  if (t == 255) bsum[blockIdx.x] = sh[255];
}

// scan3 with inline scan of bsum (replaces old scan2 kernel)
__global__ __launch_bounds__(256) void scan3_kernel(const int* __restrict__ count,
                                                    const int* __restrict__ locpre,
                                                    const int* __restrict__ bsum,
                                                    int* __restrict__ offsets,
                                                    int* __restrict__ csr,
                                                    int* __restrict__ cursor,
                                                    float* __restrict__ als1s,  // &als1[n*4]
                                                    float* __restrict__ als2s,  // &als2[n]
                                                    int n, int nb) {
  __shared__ int sh[256];
  int t = threadIdx.x;
  int v = (t < nb) ? bsum[t] : 0;
  sh[t] = v;
  __syncthreads();
  for (int off = 1; off < 256; off <<= 1) {
    int u = (t >= off) ? sh[t - off] : 0;
    __syncthreads();
    sh[t] += u;
    __syncthreads();
  }
  int bpre = (blockIdx.x == 0) ? 0 : sh[blockIdx.x - 1];
  int node = blockIdx.x * 256 + t;
  if (node >= n) return;
  int o = bpre + locpre[node];
  int cnt = count[node];
  int padlen = (cnt + 4) & ~3;
  offsets[node] = o;
  csr[o] = node;  // self-loop in slot 0
  for (int p = 1 + cnt; p < padlen; ++p) csr[o + p] = n;  // sentinel fill
  cursor[node] = 0;
  if (node == n - 1) offsets[n] = o + padlen;
  if (node == 0) {
    als1s[0] = -1e30f; als1s[1] = -1e30f; als1s[2] = -1e30f; als1s[3] = -1e30f;
    als2s[0] = -1e30f;
  }
}

__global__ __launch_bounds__(256) void scatter_kernel(const int* __restrict__ src,
                                                      const int* __restrict__ dst,
                                                      const int* __restrict__ offsets,
                                                      int* __restrict__ cursor,
                                                      int* __restrict__ csr, int E) {
  int e = blockIdx.x * blockDim.x + threadIdx.x;
  if (e < E) {
    int d = dst[e];
    int pos = atomicAdd(&cursor[d], 1);
    csr[offsets[d] + 1 + pos] = src[e];
  }
}

// ---------------- merged weight conversion ----------------
// W1 [256][256] f32 -> Bt1 [256][256] fp16 (transposed); W2 [256][64] -> Bt2 [64][256] fp16.
__global__ __launch_bounds__(256) void convW_kernel(const float* __restrict__ W1,
                                                    const float* __restrict__ W2,
                                                    _Float16* __restrict__ Bt1,
                                                    _Float16* __restrict__ Bt2) {
  int idx = blockIdx.x * blockDim.x + threadIdx.x;
  if (idx < 256 * 64) {
    int c = idx >> 6;              // output col of W1 (0..255)
    int k4 = (idx & 63) * 4;
    half4 v;
#pragma unroll
    for (int i = 0; i < 4; ++i) v[i] = (_Float16)W1[(size_t)(k4 + i) * 256 + c];
    *(half4*)&Bt1[(size_t)c * 256 + k4] = v;
  } else if (idx < 256 * 64 + 64 * 64) {
    int j = idx - 256 * 64;
    int c = j >> 6;                // output col of W2 (0..63)
    int k4 = (j & 63) * 4;
    half4 v;
#pragma unroll
    for (int i = 0; i < 4; ++i) v[i] = (_Float16)W2[(size_t)(k4 + i) * 64 + c];
    *(half4*)&Bt2[(size_t)c * 256 + k4] = v;
  }
}

// ---------------- GEMM1: xh1 = x @ W1 (fp16 MFMA) + fused alpha ----------------
// BM=128, BN=256 (full N), BK=32, 512 threads = 8 waves (2x4). Wave: WM=64, WN=64
// -> exactly one head (head = wc). A (f32) converted to fp16 in-register at staging.
__global__ __launch_bounds__(512) void gemm1_fused(
    const float* __restrict__ Af,
    const _Float16* __restrict__ Bt,
    const float* __restrict__ asrc, const float* __restrict__ adst,
    _Float16* __restrict__ xh, float* __restrict__ als, float* __restrict__ ald, int M) {
  constexpr int BM = 128, BK = 32, KTOT = 256, NW = 256;
  constexpr int MR = 4, NR = 4;
  __shared__ __align__(16) _Float16 lsA[BM * BK];
  __shared__ __align__(16) _Float16 lsB[NW * BK];
  const int tid = threadIdx.x;
  const int lane = tid & 63;
  const int w = tid >> 6;
  const int wr = w >> 2, wc = w & 3;
  const int bm = blockIdx.x * BM;

  f32x4 acc[MR][NR];
#pragma unroll
  for (int i = 0; i < MR; ++i)
#pragma unroll
    for (int j = 0; j < NR; ++j) acc[i][j] = (f32x4){0.f, 0.f, 0.f, 0.f};

  for (int k0 = 0; k0 < KTOT; k0 += BK) {
    // A stage: 128x32, one round (512 threads x 8 elems), f32 -> fp16
    {
      int row = tid >> 2, c0 = tid & 3;
      int cs = c0 ^ ((row >> 1) & 3);
      half8_t hv;
      if (bm + row < M) {
        float4 v0 = *(const float4*)&Af[(size_t)(bm + row) * 256 + k0 + c0 * 8];
        float4 v1 = *(const float4*)&Af[(size_t)(bm + row) * 256 + k0 + c0 * 8 + 4];
        hv[0] = (_Float16)v0.x; hv[1] = (_Float16)v0.y;
        hv[2] = (_Float16)v0.z; hv[3] = (_Float16)v0.w;
        hv[4] = (_Float16)v1.x; hv[5] = (_Float16)v1.y;
        hv[6] = (_Float16)v1.z; hv[7] = (_Float16)v1.w;
      } else {
#pragma unroll
        for (int i = 0; i < 8; ++i) hv[i] = (_Float16)0.f;
      }
      *(half8_t*)&lsA[row * BK + cs * 8] = hv;
    }
    // B stage: 256x32, two rounds
#pragma unroll
    for (int rnd = 0; rnd < 2; ++rnd) {
      int id = rnd * 512 + tid;
      int row = id >> 2, c0 = id & 3;
      int cs = c0 ^ ((row >> 1) & 3);
      *(half8_t*)&lsB[row * BK + cs * 8] =
          *(const half8_t*)&Bt[(size_t)row * 256 + k0 + c0 * 8];
    }
    __syncthreads();
    half8_t af[MR], bf[NR];
#pragma unroll
    for (int mr = 0; mr < MR; ++mr) {
      int rr = wr * 64 + mr * 16 + (lane & 15);
      int kc = (lane >> 4) ^ ((rr >> 1) & 3);
      af[mr] = *(const half8_t*)&lsA[rr * BK + kc * 8];
    }
#pragma unroll
    for (int nr = 0; nr < NR; ++nr) {
      int rn = wc * 64 + nr * 16 + (lane & 15);
      int kc = (lane >> 4) ^ ((rn >> 1) & 3);
      bf[nr] = *(const half8_t*)&lsB[rn * BK + kc * 8];
    }
#pragma unroll
    for (int mr = 0; mr < MR; ++mr)
#pragma unroll
      for (int nr = 0; nr < NR; ++nr)
        acc[mr][nr] = __builtin_amdgcn_mfma_f32_16x16x32_f16(af[mr], bf[nr], acc[mr][nr], 0, 0, 0);
    __syncthreads();
  }

  // epilogue: xh (fp16) + per-head alpha dots (head = wc)
  float as_[NR], ad_[NR];
#pragma unroll
  for (int nr = 0; nr < NR; ++nr) {
    int c = wc * 64 + nr * 16 + (lane & 15);
    as_[nr] = asrc[c];
    ad_[nr] = adst[c];
  }
#pragma unroll
  for (int mr = 0; mr < MR; ++mr) {
#pragma unroll
    for (int j = 0; j < 4; ++j) {
      int r = bm + wr * 64 + mr * 16 + (lane >> 4) * 4 + j;
      bool ok = r < M;
      float s = 0.f, d = 0.f;
#pragma unroll
      for (int nr = 0; nr < NR; ++nr) {
        float v = acc[mr][nr][j];
        if (ok) xh[(size_t)r * 256 + wc * 64 + nr * 16 + (lane & 15)] = (_Float16)v;
        s += v * as_[nr];
        d += v * ad_[nr];
      }
#pragma unroll
      for (int m = 1; m <= 8; m <<= 1) {
        s += __shfl_xor(s, m);
        d += __shfl_xor(d, m);
      }
      if (ok && (lane & 15) == 0) {
        als[r * 4 + wc] = s;
        ald[r * 4 + wc] = d;
      }
    }
  }
}

// ---------------- GEMM2: xh2 = A2 @ W2 (fp16) + fused alpha (H=1) ----------------
// BM=128, BN=64, BK=32, 256 threads = 4 waves (4x1): WM=32, WN=64.
__global__ __launch_bounds__(256) void gemm2_fused(
    const _Float16* __restrict__ A,
    const _Float16* __restrict__ Bt,
    const float* __restrict__ asrc, const float* __restrict__ adst,
    _Float16* __restrict__ xh, float* __restrict__ als, float* __restrict__ ald, int M) {
  constexpr int BM = 128, BK = 32, KTOT = 256, NW = 64;
  constexpr int MR = 2, NR = 4;
  __shared__ __align__(16) _Float16 lsA[BM * BK];
  __shared__ __align__(16) _Float16 lsB[NW * BK];
  const int tid = threadIdx.x;
  const int lane = tid & 63;
  const int wr = tid >> 6;
  const int bm = blockIdx.x * BM;

  f32x4 acc[MR][NR];
#pragma unroll
  for (int i = 0; i < MR; ++i)
#pragma unroll
    for (int j = 0; j < NR; ++j) acc[i][j] = (f32x4){0.f, 0.f, 0.f, 0.f};

  for (int k0 = 0; k0 < KTOT; k0 += BK) {
#pragma unroll
    for (int rnd = 0; rnd < 2; ++rnd) {
      int id = rnd * 256 + tid;
      int row = id >> 2, c0 = id & 3;
      int cs = c0 ^ ((row >> 1) & 3);
      *(half8_t*)&lsA[row * BK + cs * 8] =
          *(const half8_t*)&A[(size_t)(bm + row) * 256 + k0 + c0 * 8];
    }
    {
      int row = tid >> 2, c0 = tid & 3;
      int cs = c0 ^ ((row >> 1) & 3);
      *(half8_t*)&lsB[row * BK + cs * 8] =
          *(const half8_t*)&Bt[(size_t)row * 256 + k0 + c0 * 8];
    }
    __syncthreads();
    half8_t af[MR], bf[NR];
#pragma unroll
    for (int mr = 0; mr < MR; ++mr) {
      int rr = wr * 32 + mr * 16 + (lane & 15);
      int kc = (lane >> 4) ^ ((rr >> 1) & 3);
      af[mr] = *(const half8_t*)&lsA[rr * BK + kc * 8];
    }
#pragma unroll
    for (int nr = 0; nr < NR; ++nr) {
      int rn = nr * 16 + (lane & 15);
      int kc = (lane >> 4) ^ ((rn >> 1) & 3);
      bf[nr] = *(const half8_t*)&lsB[rn * BK + kc * 8];
    }
    __syncthreads();
#pragma unroll
    for (int mr = 0; mr < MR; ++mr)
#pragma unroll
      for (int nr = 0; nr < NR; ++nr)
        acc[mr][nr] = __builtin_amdgcn_mfma_f32_16x16x32_f16(af[mr], bf[nr], acc[mr][nr], 0, 0, 0);
  }

  float as_[NR], ad_[NR];
#pragma unroll
  for (int nr = 0; nr < NR; ++nr) {
    int c = nr * 16 + (lane & 15);
    as_[nr] = asrc[c];
    ad_[nr] = adst[c];
  }
#pragma unroll
  for (int mr = 0; mr < MR; ++mr) {
#pragma unroll
    for (int j = 0; j < 4; ++j) {
      int r = bm + wr * 32 + mr * 16 + (lane >> 4) * 4 + j;
      bool ok = r < M;
      float s = 0.f, d = 0.f;
#pragma unroll
      for (int nr = 0; nr < NR; ++nr) {
        float v = acc[mr][nr][j];
        if (ok) xh[(size_t)r * 64 + nr * 16 + (lane & 15)] = (_Float16)v;
        s += v * as_[nr];
        d += v * ad_[nr];
      }
#pragma unroll
      for (int m = 1; m <= 8; m <<= 1) {
        s += __shfl_xor(s, m);
        d += __shfl_xor(d, m);
      }
      if (ok && (lane & 15) == 0) {
        als[r] = s;
        ald[r] = d;
      }
    }
  }
}

// ---------------- aggregation ----------------
// Layer 1 (H=4): wave per node; lane owns 4 channels; head = lane>>4.
// 8-edge unrolled main loop (2x int4 csr + 8 gathers in flight), 4-edge tail
// (wave-uniform guard; padded CSR guarantees multiple of 4). elu -> fp16 A2.
__global__ __launch_bounds__(256) void agg1_kernel(const _Float16* __restrict__ xh,
                                                   const float* __restrict__ als,
                                                   const float* __restrict__ ald,
                                                   const int* __restrict__ offsets,
                                                   const int* __restrict__ csr,
                                                   const float* __restrict__ bias,
                                                   _Float16* __restrict__ A2, int n) {
  int node = (blockIdx.x * blockDim.x + threadIdx.x) >> 6;
  int lane = threadIdx.x & 63;
  if (node >= n) return;
  int h = lane >> 4;
  int beg = offsets[node], end = offsets[node + 1];
  float ad = ald[node * 4 + h];
  float den = 0.f;
  float ax = 0.f, ay = 0.f, az = 0.f, aw = 0.f;
  int e = beg;
  for (; e + 8 <= end; e += 8) {
    int4 sa = *(const int4*)&csr[e];
    int4 sb = *(const int4*)&csr[e + 4];
    float a0 = als[sa.x * 4 + h], a1 = als[sa.y * 4 + h];
    float a2 = als[sa.z * 4 + h], a3 = als[sa.w * 4 + h];
    float a4 = als[sb.x * 4 + h], a5 = als[sb.y * 4 + h];
    float a6 = als[sb.z * 4 + h], a7 = als[sb.w * 4 + h];
    half4 x0 = *(const half4*)&xh[(size_t)sa.x * 256 + 4 * lane];
    half4 x1 = *(const half4*)&xh[(size_t)sa.y * 256 + 4 * lane];
    half4 x2 = *(const half4*)&xh[(size_t)sa.z * 256 + 4 * lane];
    half4 x3 = *(const half4*)&xh[(size_t)sa.w * 256 + 4 * lane];
    half4 x4 = *(const half4*)&xh[(size_t)sb.x * 256 + 4 * lane];
    half4 x5 = *(const half4*)&xh[(size_t)sb.y * 256 + 4 * lane];
    half4 x6 = *(const half4*)&xh[(size_t)sb.z * 256 + 4 * lane];
    half4 x7 = *(const half4*)&xh[(size_t)sb.w * 256 + 4 * lane];
    float e0 = __expf(leaky02(a0 + ad));
    float e1 = __expf(leaky02(a1 + ad));
    float e2 = __expf(leaky02(a2 + ad));
    float e3 = __expf(leaky02(a3 + ad));
    float e4 = __expf(leaky02(a4 + ad));
    float e5 = __expf(leaky02(a5 + ad));
    float e6 = __expf(leaky02(a6 + ad));
    float e7 = __expf(leaky02(a7 + ad));
    den += ((e0 + e1) + (e2 + e3)) + ((e4 + e5) + (e6 + e7));
    ax += e0 * (float)x0[0] + e1 * (float)x1[0] + e2 * (float)x2[0] + e3 * (float)x3[0]
        + e4 * (float)x4[0] + e5 * (float)x5[0] + e6 * (float)x6[0] + e7 * (float)x7[0];
    ay += e0 * (float)x0[1] + e1 * (float)x1[1] + e2 * (float)x2[1] + e3 * (float)x3[1]
        + e4 * (float)x4[1] + e5 * (float)x5[1] + e6 * (float)x6[1] + e7 * (float)x7[1];
    az += e0 * (float)x0[2] + e1 * (float)x1[2] + e2 * (float)x2[2] + e3 * (float)x3[2]
        + e4 * (float)x4[2] + e5 * (float)x5[2] + e6 * (float)x6[2] + e7 * (float)x7[2];
    aw += e0 * (float)x0[3] + e1 * (float)x1[3] + e2 * (float)x2[3] + e3 * (float)x3[3]
        + e4 * (float)x4[3] + e5 * (float)x5[3] + e6 * (float)x6[3] + e7 * (float)x7[3];
  }
  if (e < end) {  // exactly one 4-group remains (wave-uniform)
    int4 s4 = *(const int4*)&csr[e];
    float a0 = als[s4.x * 4 + h], a1 = als[s4.y * 4 + h];
    float a2 = als[s4.z * 4 + h], a3 = als[s4.w * 4 + h];
    half4 x0 = *(const half4*)&xh[(size_t)s4.x * 256 + 4 * lane];
    half4 x1 = *(const half4*)&xh[(size_t)s4.y * 256 + 4 * lane];
    half4 x2 = *(const half4*)&xh[(size_t)s4.z * 256 + 4 * lane];
    half4 x3 = *(const half4*)&xh[(size_t)s4.w * 256 + 4 * lane];
    float e0 = __expf(leaky02(a0 + ad));
    float e1 = __expf(leaky02(a1 + ad));
    float e2 = __expf(leaky02(a2 + ad));
    float e3 = __expf(leaky02(a3 + ad));
    den += (e0 + e1) + (e2 + e3);
    ax += e0 * (float)x0[0] + e1 * (float)x1[0] + e2 * (float)x2[0] + e3 * (float)x3[0];
    ay += e0 * (float)x0[1] + e1 * (float)x1[1] + e2 * (float)x2[1] + e3 * (float)x3[1];
    az += e0 * (float)x0[2] + e1 * (float)x1[2] + e2 * (float)x2[2] + e3 * (float)x3[2];
    aw += e0 * (float)x0[3] + e1 * (float)x1[3] + e2 * (float)x2[3] + e3 * (float)x3[3];
  }
  float inv = 1.f / (den + 1e-16f);
  float4 b = *(const float4*)&bias[4 * lane];
  half4 o;
  o[0] = (_Float16)elu1(ax * inv + b.x);
  o[1] = (_Float16)elu1(ay * inv + b.y);
  o[2] = (_Float16)elu1(az * inv + b.z);
  o[3] = (_Float16)elu1(aw * inv + b.w);
  *(half4*)&A2[(size_t)node * 256 + 4 * lane] = o;
}

// Layer 2 (H=1, C=64): wave per node, 4 edge-groups x 16 lanes, 2x unrolled.
__global__ __launch_bounds__(256) void agg2_kernel(const _Float16* __restrict__ xh,
                                                   const float* __restrict__ als,
                                                   const float* __restrict__ ald,
                                                   const int* __restrict__ offsets,
                                                   const int* __restrict__ csr,
                                                   const float* __restrict__ bias,
                                                   float* __restrict__ out, int n) {
  int node = (blockIdx.x * blockDim.x + threadIdx.x) >> 6;
  int lane = threadIdx.x & 63;
  if (node >= n) return;
  int g = lane >> 4, li = lane & 15;
  int beg = offsets[node], end = offsets[node + 1];
  float ad = ald[node];
  float den = 0.f;
  float ax = 0.f, ay = 0.f, az = 0.f, aw = 0.f;
  int e0 = beg;
  for (; e0 + 8 <= end; e0 += 8) {
    int s0 = csr[e0 + g];
    int s1 = csr[e0 + 4 + g];
    half4 xv0 = *(const half4*)&xh[(size_t)s0 * 64 + 4 * li];
    half4 xv1 = *(const half4*)&xh[(size_t)s1 * 64 + 4 * li];
    float w0 = __expf(leaky02(als[s0] + ad));
    float w1 = __expf(leaky02(als[s1] + ad));
    den += w0 + w1;
    ax += w0 * (float)xv0[0] + w1 * (float)xv1[0];
    ay += w0 * (float)xv0[1] + w1 * (float)xv1[1];
    az += w0 * (float)xv0[2] + w1 * (float)xv1[2];
    aw += w0 * (float)xv0[3] + w1 * (float)xv1[3];
  }
  if (e0 < end) {
    int s = csr[e0 + g];
    half4 xv = *(const half4*)&xh[(size_t)s * 64 + 4 * li];
    float w = __expf(leaky02(als[s] + ad));
    den += w;
    ax += w * (float)xv[0]; ay += w * (float)xv[1];
    az += w * (float)xv[2]; aw += w * (float)xv[3];
  }
#pragma unroll
  for (int m = 16; m <= 32; m <<= 1) {
    den += __shfl_xor(den, m);
    ax += __shfl_xor(ax, m);
    ay += __shfl_xor(ay, m);
    az += __shfl_xor(az, m);
    aw += __shfl_xor(aw, m);
  }
  if (g == 0) {
    float inv = 1.f / (den + 1e-16f);
    float4 b = *(const float4*)&bias[4 * li];
    float4 o;
    o.x = elu1(ax * inv + b.x);
    o.y = elu1(ay * inv + b.y);
    o.z = elu1(az * inv + b.z);
    o.w = elu1(aw * inv + b.w);
    *(float4*)&out[(size_t)node * 64 + 4 * li] = o;
  }
}

// ---------------- launch ----------------

extern "C" void kernel_launch(void* const* d_in, const int* in_sizes, int n_in,
                              void* d_out, int out_size, void* d_ws, size_t ws_size,
                              hipStream_t stream) {
  const float* x   = (const float*)d_in[0];
  const int*   ei  = (const int*)d_in[1];
  const float* W1  = (const float*)d_in[2];
  const float* as1 = (const float*)d_in[3];
  const float* ad1 = (const float*)d_in[4];
  const float* b1  = (const float*)d_in[5];
  const float* W2  = (const float*)d_in[6];
  const float* as2 = (const float*)d_in[7];
  const float* ad2 = (const float*)d_in[8];
  const float* b2  = (const float*)d_in[9];
  float* out = (float*)d_out;

  const int E = in_sizes[1] / 2;    // 800000
  const int n = in_sizes[0] / 256;  // 50000
  const int Mpad = ((n + 127) / 128) * 128;  // 50048
  const int nb = (n + 255) / 256;   // scan blocks (196 <= 256)

  size_t off = 0;
  auto alloc = [&](size_t bytes) -> void* {
    void* p = (char*)d_ws + off;
    off += (bytes + 511) & ~(size_t)511;
    return p;
  };
  _Float16* xh  = (_Float16*)alloc((size_t)(n + 1) * 256 * 2);  // xh1 (+sentinel row); reused xh2
  _Float16* A2  = (_Float16*)alloc((size_t)Mpad * 256 * 2);     // layer-1 output, fp16
  _Float16* Bt1 = (_Float16*)alloc((size_t)256 * 256 * 2);
  _Float16* Bt2 = (_Float16*)alloc((size_t)64 * 256 * 2);
  float* als1v = (float*)alloc((size_t)(n + 1) * 4 * 4);
  float* ald1v = (float*)alloc((size_t)n * 4 * 4);
  float* als2v = (float*)alloc((size_t)(n + 1) * 4);
  float* ald2v = (float*)alloc((size_t)n * 4);
  int* count   = (int*)alloc((size_t)n * 4);
  int* cursor  = (int*)alloc((size_t)n * 4);
  int* offsets = (int*)alloc((size_t)(n + 1) * 4);
  int* locpre  = (int*)alloc((size_t)n * 4);
  int* bsum    = (int*)alloc(256 * 4);
  int* csr     = (int*)alloc((size_t)(E + 4 * n) * 4);

  const int* srcv = ei;
  const int* dstv = ei + E;

  // CSR (padded segments)
  hipMemsetAsync(count, 0, (size_t)n * 4, stream);
  count_kernel<<<(E + 255) / 256, 256, 0, stream>>>(dstv, count, E);
  scan1_kernel<<<nb, 256, 0, stream>>>(count, locpre, bsum, n);
  scan3_kernel<<<nb, 256, 0, stream>>>(count, locpre, bsum, offsets, csr, cursor,
                                       als1v + (size_t)n * 4, als2v + n, n, nb);
  scatter_kernel<<<(E + 255) / 256, 256, 0, stream>>>(srcv, dstv, offsets, cursor, csr, E);

  // weight conversions (merged)
  convW_kernel<<<(256 * 64 + 64 * 64 + 255) / 256, 256, 0, stream>>>(W1, W2, Bt1, Bt2);

  // Layer 1
  gemm1_fused<<<Mpad / 128, 512, 0, stream>>>(x, Bt1, as1, ad1, xh, als1v, ald1v, n);
  agg1_kernel<<<(n + 3) / 4, 256, 0, stream>>>(xh, als1v, ald1v, offsets, csr, b1, A2, n);

  // Layer 2 (xh2 aliases xh)
  gemm2_fused<<<Mpad / 128, 256, 0, stream>>>(A2, Bt2, as2, ad2, xh, als2v, ald2v, n);
  agg2_kernel<<<(n + 3) / 4, 256, 0, stream>>>(xh, als2v, ald2v, offsets, csr, b2, out, n);
}